// Round 10
// baseline (474.802 us; speedup 1.0000x reference)
//
#include <hip/hip_runtime.h>
#include <hip/hip_bf16.h>
#include <cstdint>
#include <cstddef>

using bf16 = __hip_bfloat16;
typedef __attribute__((ext_vector_type(8))) short short8v;   // MFMA A/B frag: 8 bf16
typedef __attribute__((ext_vector_type(4))) short short4v;   // 4 bf16 (b64 load/store)
typedef __attribute__((ext_vector_type(4))) float float4v;   // MFMA C/D frag

__device__ inline float b2f(short s) {
  union { float f; uint32_t u; } z; z.u = ((uint32_t)(uint16_t)s) << 16; return z.f;
}
__device__ inline short f2b(float f) {
  bf16 h = __float2bfloat16(f);
  return *reinterpret_cast<short*>(&h);
}

typedef const __attribute__((address_space(1))) uint32_t* gas1p;
typedef __attribute__((address_space(3))) uint32_t* las3p;
__device__ inline void gload_lds16(const void* g, void* l) {
  __builtin_amdgcn_global_load_lds((gas1p)g, (las3p)l, 16, 0, 0);
}

// T1 XCD swizzle (gemm_pipe only).
__device__ inline void xcd_swizzle(int& bx, int& by, int& bz) {
  const int gx = gridDim.x, gy = gridDim.y;
  const int nwg = gx * gy * gridDim.z;
  const int wgid = blockIdx.x + gx * (blockIdx.y + gy * blockIdx.z);
  const int swz = (wgid & 7) * (nwg >> 3) + (wgid >> 3);
  bx = swz % gx;
  by = (swz / gx) % gy;
  bz = swz / (gx * gy);
}

// ---------------------------------------------------------------------------
// 256x256-tile GEMM, 8 waves (2x4), per-wave output 128x64, BK=32, 2-phase.
// (round 9: pulled FF1/QKV out of the top-5 — per-FLOP traffic halved vs 128².)
// ---------------------------------------------------------------------------
__global__ __launch_bounds__(512, 2) void gemm_bt256(
    const bf16* __restrict__ A, const bf16* __restrict__ Bt,
    const float* __restrict__ bias, void* __restrict__ C,
    int K, int ldc, int relu_mode, int out_f32) {
  __shared__ __align__(16) bf16 As[256 * 32];
  __shared__ __align__(16) bf16 Bs[256 * 32];
  const int tid = threadIdx.x;             // 0..511
  const int w = tid >> 6, lane = tid & 63;
  const int quad = lane >> 4, l16 = lane & 15;
  const int wrow = (w >> 2) * 128, wcol = (w & 3) * 64;   // 2x4 wave grid
  const int mbase = blockIdx.y * 256, nbase = blockIdx.x * 256;
  const int row0 = tid >> 2, p0 = tid & 3;
  const int row1 = (tid + 512) >> 2, p1 = (tid + 512) & 3;

  float4v acc[8][4];
#pragma unroll
  for (int i = 0; i < 8; i++)
#pragma unroll
    for (int j = 0; j < 4; j++) acc[i][j] = (float4v){0.f, 0.f, 0.f, 0.f};

  for (int k0 = 0; k0 < K; k0 += 32) {
    __syncthreads();  // prev iter's ds_reads done before restage
    gload_lds16(A + (size_t)(mbase + row0) * K + k0 + p0 * 8, (char*)As + w * 1024);
    gload_lds16(A + (size_t)(mbase + row1) * K + k0 + p1 * 8, (char*)As + 8192 + w * 1024);
    gload_lds16(Bt + (size_t)(nbase + row0) * K + k0 + p0 * 8, (char*)Bs + w * 1024);
    gload_lds16(Bt + (size_t)(nbase + row1) * K + k0 + p1 * 8, (char*)Bs + 8192 + w * 1024);
    __syncthreads();  // vmcnt drained -> tiles valid

    short8v a[8], b[4];
#pragma unroll
    for (int mt = 0; mt < 8; mt++)
      a[mt] = *reinterpret_cast<const short8v*>(As + (wrow + mt * 16 + l16) * 32 + quad * 8);
#pragma unroll
    for (int nt = 0; nt < 4; nt++)
      b[nt] = *reinterpret_cast<const short8v*>(Bs + (wcol + nt * 16 + l16) * 32 + quad * 8);
#pragma unroll
    for (int mt = 0; mt < 8; mt++)
#pragma unroll
      for (int nt = 0; nt < 4; nt++)
        acc[mt][nt] = __builtin_amdgcn_mfma_f32_16x16x32_bf16(a[mt], b[nt], acc[mt][nt], 0, 0, 0);
  }

  // epilogue: D row = quad*4+reg, col = lane&15
#pragma unroll
  for (int nt = 0; nt < 4; nt++) {
    int col = nbase + wcol + nt * 16 + l16;
    float bv = bias[col];
#pragma unroll
    for (int mt = 0; mt < 8; mt++) {
      int row = mbase + wrow + mt * 16 + quad * 4;
#pragma unroll
      for (int r = 0; r < 4; r++) {
        float v = acc[mt][nt][r] + bv;
        if (relu_mode) v = fmaxf(v, 0.f);
        size_t idx = (size_t)(row + r) * ldc + col;
        if (out_f32) ((float*)C)[idx] = v;
        else         ((short*)C)[idx] = f2b(v);
      }
    }
  }
}

// ---------------------------------------------------------------------------
// Pipelined split-K GEMM for grid-limited shapes (WO, FF2). 3-buffer LDS,
// counted vmcnt + T1 XCD swizzle. blockIdx.z selects a K-slice; partial sums
// atomicAdd into fp32 C (bias pre-initialized).
// ---------------------------------------------------------------------------
__global__ __launch_bounds__(256) void gemm_pipe(
    const bf16* __restrict__ A, const bf16* __restrict__ Bt,
    float* __restrict__ C, int K, int ldc, int k_len) {
  __shared__ __align__(16) bf16 As[3][128 * 32];
  __shared__ __align__(16) bf16 Bs[3][128 * 32];
  const int tid = threadIdx.x;
  const int w = tid >> 6, lane = tid & 63;
  const int quad = lane >> 4, l16 = lane & 15;
  const int wrow = (w >> 1) * 64, wcol = (w & 1) * 64;
  int bx, by, bz;
  xcd_swizzle(bx, by, bz);
  const int mbase = by * 128, nbase = bx * 128;
  const int c0 = w * 128 + lane;           // chunk ids c0 and c0+64
  const int row0 = c0 >> 2, p0 = c0 & 3;
  const int row1 = (c0 + 64) >> 2, p1 = (c0 + 64) & 3;
  const int kbase = bz * k_len;

  const bf16* ag0 = A + (size_t)(mbase + row0) * K + kbase + p0 * 8;
  const bf16* ag1 = A + (size_t)(mbase + row1) * K + kbase + p1 * 8;
  const bf16* bg0 = Bt + (size_t)(nbase + row0) * K + kbase + p0 * 8;
  const bf16* bg1 = Bt + (size_t)(nbase + row1) * K + kbase + p1 * 8;

  auto stage = [&](int t, int bi) {
    const int ko = t * 32;
    char* da = (char*)As + bi * 8192 + w * 2048;
    char* db = (char*)Bs + bi * 8192 + w * 2048;
    gload_lds16(ag0 + ko, da);
    gload_lds16(ag1 + ko, da + 1024);
    gload_lds16(bg0 + ko, db);
    gload_lds16(bg1 + ko, db + 1024);
  };

  float4v acc[4][4];
  for (int i = 0; i < 4; i++)
    for (int j = 0; j < 4; j++) acc[i][j] = (float4v){0.f, 0.f, 0.f, 0.f};

  const int KT = k_len >> 5;
  // prologue: tiles 0,1 in flight (8 outstanding per wave)
  stage(0, 0);
  stage(1, 1);

  for (int kt = 0; kt < KT; kt++) {
    const int pb = kt % 3;
    // drain tile kt's own 4 loads; tile kt+1's 4 may remain in flight
    if (kt + 1 < KT) asm volatile("s_waitcnt vmcnt(4)" ::: "memory");
    else             asm volatile("s_waitcnt vmcnt(0)" ::: "memory");
    __builtin_amdgcn_s_barrier();
    asm volatile("" ::: "memory");   // compiler fence: no LDS-op motion across barrier

    if (kt + 2 < KT) stage(kt + 2, (kt + 2) % 3);

    short8v a[4], b[4];
    for (int mt = 0; mt < 4; mt++)
      a[mt] = *reinterpret_cast<const short8v*>(&As[pb][(wrow + mt * 16 + l16) * 32 + quad * 8]);
    for (int nt = 0; nt < 4; nt++)
      b[nt] = *reinterpret_cast<const short8v*>(&Bs[pb][(wcol + nt * 16 + l16) * 32 + quad * 8]);
    for (int mt = 0; mt < 4; mt++)
      for (int nt = 0; nt < 4; nt++)
        acc[mt][nt] = __builtin_amdgcn_mfma_f32_16x16x32_bf16(a[mt], b[nt], acc[mt][nt], 0, 0, 0);
  }

  // epilogue: partial-sum atomicAdd (C pre-initialized with bias)
  for (int nt = 0; nt < 4; nt++) {
    int col = nbase + wcol + nt * 16 + l16;
    for (int mt = 0; mt < 4; mt++) {
      int row = mbase + wrow + mt * 16 + quad * 4;
      for (int r = 0; r < 4; r++)
        atomicAdd(&C[(size_t)(row + r) * ldc + col], acc[mt][nt][r]);
    }
  }
}

// C[row, 0..N) = bias[0..N), fp32. grid = rows, block 256, N = 1024.
__global__ __launch_bounds__(256) void bias_init(
    const float* __restrict__ bias, float* __restrict__ C) {
  int c = threadIdx.x * 4;
  float4 bv = *reinterpret_cast<const float4*>(bias + c);
  *reinterpret_cast<float4*>(C + (size_t)blockIdx.x * 1024 + c) = bv;
}

// ---------------------------------------------------------------------------
// Flash attention v9: 16 q-rows/wave, grid (32,32) = 1024 blocks = 4/CU.
// This is round-1's occupancy split retried WITH cooperative K/V staging:
// round-1 regressed because each wave redundantly loaded K from global
// (per-CU VMEM doubled); that mechanism was removed in round 2. Now total
// softmax VALU and MFMA are unchanged, per-wave critical chain halves, and
// independent chains per CU double (16 waves). Only cost: 2x per-CU K/V
// staging from L2 (~24 KB/iter, far under L2 BW).
// ---------------------------------------------------------------------------
__global__ __launch_bounds__(256) void attn_kernel(
    const bf16* __restrict__ qkv, const int* __restrict__ mask,
    bf16* __restrict__ ao) {
  __shared__ __align__(16) short Vt[2][64 * 40];   // [buf][d][kv], pitch 40
  __shared__ __align__(16) short Ks[2][32 * 64];   // [buf][kv][d], row-XOR-swizzled

  const int tid = threadIdx.x;
  const int w = tid >> 6, lane = tid & 63;
  const int quad = lane >> 4, l16 = lane & 15;
  const int bh = blockIdx.y, b = bh >> 4;
  const int row0 = bh * 128;                 // row base in qkv [4096,3072]
  const int qbase = blockIdx.x * 64 + w * 16;   // wave's 16 q rows
  const int kvp = tid & 15, dg = tid >> 4;   // V stager: kv rows 2kvp,2kvp+1; d 4dg..+3
  const int krow = tid >> 3, kc = tid & 7;   // K stager: row krow, d chunk kc (8 elems)

  // Q fragments (B-operand of swapped QK^T); Q is pre-scaled by log2(e)/8
  short8v aq[2];
  for (int dh = 0; dh < 2; dh++) {
    int local = (qbase + l16) * 64 + dh * 32 + quad * 8;
    aq[dh] = *reinterpret_cast<const short8v*>(
        qkv + (size_t)(row0 + (local >> 10)) * 3072 + (local & 1023));
  }

  // K stage pointer (one b128 per thread covers the 32x64 tile)
  const bf16* pks;
  {
    int local = krow * 64 + kc * 8;
    pks = qkv + (size_t)(row0 + (local >> 10)) * 3072 + (local & 1023) + 1024;
  }
  // V stage pointers (2 kv rows x 4 d per thread)
  const bf16* pva;
  const bf16* pvb;
  {
    int la = (2 * kvp) * 64 + dg * 4;
    pva = qkv + (size_t)(row0 + (la >> 10)) * 3072 + (la & 1023) + 2048;
    int lb = (2 * kvp + 1) * 64 + dg * 4;
    pvb = qkv + (size_t)(row0 + (lb >> 10)) * 3072 + (lb & 1023) + 2048;
  }
  const int* pm = mask + b * 2048 + quad * 4;

  float4v o[4];
  for (int nt = 0; nt < 4; nt++) o[nt] = (float4v){0.f, 0.f, 0.f, 0.f};
  float4v lacc = (float4v){0.f, 0.f, 0.f, 0.f};
  short8v vone;
  for (int j = 0; j < 8; j++) vone[j] = (short)0x3F80;  // bf16 1.0 x8

  // prologue: load + stage tile 0
  short8v kreg;
  short4v va, vb;
  kreg = *reinterpret_cast<const short8v*>(pks);
  va = *reinterpret_cast<const short4v*>(pva);
  vb = *reinterpret_cast<const short4v*>(pvb);
  int4 mc0 = *reinterpret_cast<const int4*>(pm);
  int4 mc1 = *reinterpret_cast<const int4*>(pm + 16);
  pks += 6144; pva += 6144; pvb += 6144; pm += 32;
  *reinterpret_cast<short8v*>(&Ks[0][krow * 64 + ((kc ^ (krow & 7)) << 3)]) = kreg;
  {
    uint32_t* vt = reinterpret_cast<uint32_t*>(&Vt[0][0]);
    for (int i = 0; i < 4; i++)
      vt[(dg * 4 + i) * 20 + kvp] =
          ((uint32_t)(uint16_t)vb[i] << 16) | (uint16_t)(uint16_t)va[i];
  }
  __syncthreads();

  for (int it = 0; it < 64; it++) {
    const int pb = it & 1;
    short8v knreg;
    short4v vna, vnb;
    int4 mn0, mn1;
    if (it < 63) {
      knreg = *reinterpret_cast<const short8v*>(pks);
      vna = *reinterpret_cast<const short4v*>(pva);
      vnb = *reinterpret_cast<const short4v*>(pvb);
      mn0 = *reinterpret_cast<const int4*>(pm);
      mn1 = *reinterpret_cast<const int4*>(pm + 16);
      pks += 6144; pva += 6144; pvb += 6144; pm += 32;
    }

    // K fragments from LDS (swizzled read: chunk (dh*4+quad) ^ (row&7))
    short8v kc_[2][2];
    for (int s = 0; s < 2; s++)
      for (int dh = 0; dh < 2; dh++) {
        int row = s * 16 + l16;
        kc_[s][dh] = *reinterpret_cast<const short8v*>(
            &Ks[pb][row * 64 + (((dh * 4 + quad) ^ (row & 7)) << 3)]);
      }

    // QK^T (swapped): st[s][r] = score(q=l16, kv=16s+4*quad+r)
    float4v st[2];
    for (int s = 0; s < 2; s++) {
      float4v t = (float4v){0.f, 0.f, 0.f, 0.f};
      t = __builtin_amdgcn_mfma_f32_16x16x32_bf16(kc_[s][0], aq[0], t, 0, 0, 0);
      t = __builtin_amdgcn_mfma_f32_16x16x32_bf16(kc_[s][1], aq[1], t, 0, 0, 0);
      st[s] = t;
    }

    // softmax numerator + in-register P-fragment assembly (no LDS)
    short8v pf;
    {
      float ev[2][4];
      for (int s = 0; s < 2; s++) {
        int4 mv = s ? mc1 : mc0;
        int mm[4] = {mv.x, mv.y, mv.z, mv.w};
        for (int r = 0; r < 4; r++) {
          float y = st[s][r];                       // already exp2-arg units
          y = (mm[r] == 0) ? -1.4427e-12f : y;      // faithful mask semantics
          ev[s][r] = __builtin_amdgcn_exp2f(y);
        }
      }
      uint32_t a0, a1, b0, b1;
      asm("v_cvt_pk_bf16_f32 %0, %1, %2" : "=v"(a0) : "v"(ev[0][0]), "v"(ev[0][1]));
      asm("v_cvt_pk_bf16_f32 %0, %1, %2" : "=v"(a1) : "v"(ev[0][2]), "v"(ev[0][3]));
      asm("v_cvt_pk_bf16_f32 %0, %1, %2" : "=v"(b0) : "v"(ev[1][0]), "v"(ev[1][1]));
      asm("v_cvt_pk_bf16_f32 %0, %1, %2" : "=v"(b1) : "v"(ev[1][2]), "v"(ev[1][3]));
      // halves: lanes<32 hold A-family (s=0), >=32 B-family (s=1)
      asm("v_permlane32_swap_b32 %0, %1" : "+v"(b0), "+v"(a0));
      asm("v_permlane16_swap_b32 %0, %1" : "+v"(b0), "+v"(a0));
      asm("v_permlane32_swap_b32 %0, %1" : "+v"(b1), "+v"(a1));
      asm("v_permlane16_swap_b32 %0, %1" : "+v"(b1), "+v"(a1));
      union { short8v s8; uint32_t u[4]; } pfu;
      pfu.u[0] = a0; pfu.u[1] = a1; pfu.u[2] = b0; pfu.u[3] = b1;
      pf = pfu.s8;
    }

    lacc = __builtin_amdgcn_mfma_f32_16x16x32_bf16(pf, vone, lacc, 0, 0, 0);
    for (int nt = 0; nt < 4; nt++) {
      short8v bv = *reinterpret_cast<const short8v*>(&Vt[pb][(nt * 16 + l16) * 40 + quad * 8]);
      o[nt] = __builtin_amdgcn_mfma_f32_16x16x32_bf16(pf, bv, o[nt], 0, 0, 0);
    }

    if (it < 63) {
      *reinterpret_cast<short8v*>(&Ks[1 - pb][krow * 64 + ((kc ^ (krow & 7)) << 3)]) = knreg;
      uint32_t* vt = reinterpret_cast<uint32_t*>(&Vt[1 - pb][0]);
      for (int i = 0; i < 4; i++)
        vt[(dg * 4 + i) * 20 + kvp] =
            ((uint32_t)(uint16_t)vnb[i] << 16) | (uint16_t)(uint16_t)vna[i];
      mc0 = mn0; mc1 = mn1;
    }
    __syncthreads();
  }

  // lacc[r] = rowsum(P) for q row quad*4+r (all 16 cols identical)
  for (int r = 0; r < 4; r++) {
    float linv = 1.0f / lacc[r];
    int qg = qbase + quad * 4 + r;
    for (int nt = 0; nt < 4; nt++) {
      int d = nt * 16 + l16;
      ao[(size_t)bh * 131072 + (size_t)qg * 64 + d] = __float2bfloat16(o[nt][r] * linv);
    }
  }
}

// ---------------------------------------------------------------------------
// out = LN(a + xres); unbiased std (ddof=1), /(std + 1e-12). One block / row.
// ---------------------------------------------------------------------------
__global__ __launch_bounds__(256) void ln_resid(
    const void* __restrict__ a, const void* __restrict__ xres,
    const float* __restrict__ gamma, const float* __restrict__ beta,
    void* __restrict__ out, int a_f32, int x_f32, int out_f32) {
  __shared__ float red[8];
  const int row = blockIdx.x, tid = threadIdx.x;
  const int w = tid >> 6, lane = tid & 63;
  const size_t base = (size_t)row * 1024;
  float v[4]; float sum = 0.f, ss = 0.f;
  for (int i = 0; i < 4; i++) {
    int c = tid + i * 256;
    float av = a_f32 ? ((const float*)a)[base + c] : b2f(((const short*)a)[base + c]);
    float xv = x_f32 ? ((const float*)xres)[base + c] : b2f(((const short*)xres)[base + c]);
    v[i] = av + xv;
    sum += v[i]; ss += v[i] * v[i];
  }
  for (int off = 1; off < 64; off <<= 1) {
    sum += __shfl_xor(sum, off);
    ss  += __shfl_xor(ss, off);
  }
  if (lane == 0) { red[w * 2] = sum; red[w * 2 + 1] = ss; }
  __syncthreads();
  sum = red[0] + red[2] + red[4] + red[6];
  ss  = red[1] + red[3] + red[5] + red[7];
  float mean = sum * (1.0f / 1024.0f);
  float var = (ss - 1024.0f * mean * mean) * (1.0f / 1023.0f);
  var = fmaxf(var, 0.f);
  float rden = 1.0f / (sqrtf(var) + 1e-12f);
  for (int i = 0; i < 4; i++) {
    int c = tid + i * 256;
    float y = gamma[c] * ((v[i] - mean) * rden) + beta[c];
    if (out_f32) ((float*)out)[base + c] = y;
    else         ((short*)out)[base + c] = f2b(y);
  }
}

// out(bf16)[c*R + r] = in(f32)[r*C + c] * scale; R,C % 32 == 0.
__global__ __launch_bounds__(256) void transpose_k(
    const float* __restrict__ in, bf16* __restrict__ out, int R, int C,
    float scale) {
  __shared__ short t[32][33];
  const int tx = threadIdx.x, ty = threadIdx.y;
  const int cb = blockIdx.x * 32, rb = blockIdx.y * 32;
  for (int j = 0; j < 4; j++)
    t[ty + j * 8][tx] = f2b(in[(size_t)(rb + ty + j * 8) * C + cb + tx] * scale);
  __syncthreads();
  for (int j = 0; j < 4; j++)
    ((short*)out)[(size_t)(cb + ty + j * 8) * R + rb + tx] = t[tx][ty + j * 8];
}

// q-bias scaled by log2(e)/8 to match the pre-scaled Q projection.
__global__ __launch_bounds__(256) void concat3(
    const float* __restrict__ a, const float* __restrict__ b,
    const float* __restrict__ c, float* __restrict__ out) {
  int i = blockIdx.x * 256 + threadIdx.x;  // grid 12 -> 3072
  float v;
  if (i < 1024)       v = a[i] * 0.18033688f;
  else if (i < 2048)  v = b[i - 1024];
  else                v = c[i - 2048];
  out[i] = v;
}

__global__ __launch_bounds__(256) void cast_f32_bf16(
    const float* __restrict__ in, bf16* __restrict__ out) {
  int i0 = (blockIdx.x * 256 + threadIdx.x) * 4;
  float4 f = *reinterpret_cast<const float4*>(in + i0);
  short* o = (short*)out + i0;
  o[0] = f2b(f.x); o[1] = f2b(f.y); o[2] = f2b(f.z); o[3] = f2b(f.w);
}

// ---------------------------------------------------------------------------
extern "C" void kernel_launch(void* const* d_in, const int* in_sizes, int n_in,
                              void* d_out, int out_size, void* d_ws, size_t ws_size,
                              hipStream_t stream) {
  (void)in_sizes; (void)n_in; (void)out_size; (void)ws_size;
  const float* x    = (const float*)d_in[0];
  const int*   mask = (const int*)d_in[1];
  const float* wq_w = (const float*)d_in[2];
  const float* wq_b = (const float*)d_in[3];
  const float* wk_w = (const float*)d_in[4];
  const float* wk_b = (const float*)d_in[5];
  const float* wv_w = (const float*)d_in[6];
  const float* wv_b = (const float*)d_in[7];
  const float* wo_w = (const float*)d_in[8];
  const float* wo_b = (const float*)d_in[9];
  const float* g1   = (const float*)d_in[10];
  const float* be1  = (const float*)d_in[11];
  const float* f1w  = (const float*)d_in[12];
  const float* f1b  = (const float*)d_in[13];
  const float* f2w  = (const float*)d_in[14];
  const float* f2b_ = (const float*)d_in[15];
  const float* g2   = (const float*)d_in[16];
  const float* be2  = (const float*)d_in[17];
  float* out = (float*)d_out;
  char* ws = (char*)d_ws;

  // ws layout (peak 48 MiB, time-shared):
  //  [0,24M)   QKV (ph2-3) -> PROJ fp32 [0,16M) (ph4-5) -> H [0,32M) (ph6-7)
  //  [24M,32M) Xbf (ph1-2) -> AO (ph3-4)
  //  [32M,40M) X1  (ph5-8)
  //  [40M,48M) WT  (transposed weights, per-phase)  + BQKV fp32 tail
  bf16*  QKV  = (bf16*)(ws + 0);
  bf16*  Xbf  = (bf16*)(ws + 25165824);
  bf16*  AO   = (bf16*)(ws + 25165824);
  float* PROJ = (float*)(ws + 0);
  bf16*  H    = (bf16*)(ws + 0);
  bf16*  X1   = (bf16*)(ws + 33554432);
  bf16*  WT   = (bf16*)(ws + 41943040);
  float* BQKV = (float*)(ws + 48234496);

  const float QSCALE = 0.18033688f;  // (1/sqrt(64)) * log2(e)

  dim3 tb(32, 8);
  // phase 1: casts + QKV weights (wq pre-scaled for exp2-direct softmax)
  cast_f32_bf16<<<dim3(4096), dim3(256), 0, stream>>>(x, Xbf);
  transpose_k<<<dim3(32, 32), tb, 0, stream>>>(wq_w, WT, 1024, 1024, QSCALE);
  transpose_k<<<dim3(32, 32), tb, 0, stream>>>(wk_w, WT + 1024 * 1024, 1024, 1024, 1.0f);
  transpose_k<<<dim3(32, 32), tb, 0, stream>>>(wv_w, WT + 2 * 1024 * 1024, 1024, 1024, 1.0f);
  concat3<<<dim3(12), dim3(256), 0, stream>>>(wq_b, wk_b, wv_b, BQKV);
  // phase 2: fused QKV projection [4096,1024]@[3072,1024]^T -> bf16 (256² tile)
  gemm_bt256<<<dim3(12, 16), dim3(512), 0, stream>>>(Xbf, WT, BQKV, QKV, 1024, 3072, 0, 0);
  // phase 3: attention (1024 blocks: 32 q-blocks x 32 bh, 4/CU — cooperative
  // K/V staging makes this occupancy split safe, unlike round 1)
  attn_kernel<<<dim3(32, 32), dim3(256), 0, stream>>>(QKV, mask, AO);
  // phase 4: output projection — counted-vmcnt pipeline, split-K=2, fp32
  // atomic into PROJ
  transpose_k<<<dim3(32, 32), tb, 0, stream>>>(wo_w, WT, 1024, 1024, 1.0f);
  bias_init<<<dim3(4096), dim3(256), 0, stream>>>(wo_b, PROJ);
  gemm_pipe<<<dim3(8, 32, 2), dim3(256), 0, stream>>>(AO, WT, PROJ, 1024, 1024, 512);
  // phase 5: LN1 (a = PROJ fp32, xres = original fp32 x)
  ln_resid<<<dim3(4096), dim3(256), 0, stream>>>(PROJ, x, g1, be1, X1, 1, 1, 0);
  // phase 6: FFN up (256² tile, 256 blocks = 1/CU, 8 waves)
  transpose_k<<<dim3(128, 32), tb, 0, stream>>>(f1w, WT, 1024, 4096, 1.0f);
  gemm_bt256<<<dim3(16, 16), dim3(512), 0, stream>>>(X1, WT, f1b, H, 1024, 4096, 1, 0);
  // phase 7: FFN down — counted-vmcnt pipeline, split-K=2, fp32 atomic
  // straight into d_out
  transpose_k<<<dim3(32, 128), tb, 0, stream>>>(f2w, WT, 4096, 1024, 1.0f);
  bias_init<<<dim3(4096), dim3(256), 0, stream>>>(f2b_, out);
  gemm_pipe<<<dim3(8, 32, 2), dim3(256), 0, stream>>>(H, WT, out, 4096, 1024, 2048);
  // phase 8: LN2 in-place on d_out (fp32 a, bf16 xres, fp32 out)
  ln_resid<<<dim3(4096), dim3(256), 0, stream>>>(out, X1, g2, be2, out, 1, 0, 1);
}

// Round 11
// 441.946 us; speedup vs baseline: 1.0743x; 1.0743x over previous
//
#include <hip/hip_runtime.h>
#include <hip/hip_bf16.h>
#include <cstdint>
#include <cstddef>

using bf16 = __hip_bfloat16;
typedef __attribute__((ext_vector_type(8))) short short8v;   // MFMA A/B frag: 8 bf16
typedef __attribute__((ext_vector_type(4))) short short4v;   // 4 bf16 (b64 load/store)
typedef __attribute__((ext_vector_type(4))) float float4v;   // MFMA C/D frag

__device__ inline float b2f(short s) {
  union { float f; uint32_t u; } z; z.u = ((uint32_t)(uint16_t)s) << 16; return z.f;
}
__device__ inline short f2b(float f) {
  bf16 h = __float2bfloat16(f);
  return *reinterpret_cast<short*>(&h);
}

typedef const __attribute__((address_space(1))) uint32_t* gas1p;
typedef __attribute__((address_space(3))) uint32_t* las3p;
__device__ inline void gload_lds16(const void* g, void* l) {
  __builtin_amdgcn_global_load_lds((gas1p)g, (las3p)l, 16, 0, 0);
}

// T1 XCD swizzle (gemm_pipe only).
__device__ inline void xcd_swizzle(int& bx, int& by, int& bz) {
  const int gx = gridDim.x, gy = gridDim.y;
  const int nwg = gx * gy * gridDim.z;
  const int wgid = blockIdx.x + gx * (blockIdx.y + gy * blockIdx.z);
  const int swz = (wgid & 7) * (nwg >> 3) + (wgid >> 3);
  bx = swz % gx;
  by = (swz / gx) % gy;
  bz = swz / (gx * gy);
}

// ---------------------------------------------------------------------------
// 256x256-tile GEMM, 8 waves (2x4), per-wave output 128x64, BK=32, 2-phase.
// (round 9: pulled FF1/QKV out of the top-5 — per-FLOP traffic halved vs 128².)
// ---------------------------------------------------------------------------
__global__ __launch_bounds__(512, 2) void gemm_bt256(
    const bf16* __restrict__ A, const bf16* __restrict__ Bt,
    const float* __restrict__ bias, void* __restrict__ C,
    int K, int ldc, int relu_mode, int out_f32) {
  __shared__ __align__(16) bf16 As[256 * 32];
  __shared__ __align__(16) bf16 Bs[256 * 32];
  const int tid = threadIdx.x;             // 0..511
  const int w = tid >> 6, lane = tid & 63;
  const int quad = lane >> 4, l16 = lane & 15;
  const int wrow = (w >> 2) * 128, wcol = (w & 3) * 64;   // 2x4 wave grid
  const int mbase = blockIdx.y * 256, nbase = blockIdx.x * 256;
  const int row0 = tid >> 2, p0 = tid & 3;
  const int row1 = (tid + 512) >> 2, p1 = (tid + 512) & 3;

  float4v acc[8][4];
#pragma unroll
  for (int i = 0; i < 8; i++)
#pragma unroll
    for (int j = 0; j < 4; j++) acc[i][j] = (float4v){0.f, 0.f, 0.f, 0.f};

  for (int k0 = 0; k0 < K; k0 += 32) {
    __syncthreads();  // prev iter's ds_reads done before restage
    gload_lds16(A + (size_t)(mbase + row0) * K + k0 + p0 * 8, (char*)As + w * 1024);
    gload_lds16(A + (size_t)(mbase + row1) * K + k0 + p1 * 8, (char*)As + 8192 + w * 1024);
    gload_lds16(Bt + (size_t)(nbase + row0) * K + k0 + p0 * 8, (char*)Bs + w * 1024);
    gload_lds16(Bt + (size_t)(nbase + row1) * K + k0 + p1 * 8, (char*)Bs + 8192 + w * 1024);
    __syncthreads();  // vmcnt drained -> tiles valid

    short8v a[8], b[4];
#pragma unroll
    for (int mt = 0; mt < 8; mt++)
      a[mt] = *reinterpret_cast<const short8v*>(As + (wrow + mt * 16 + l16) * 32 + quad * 8);
#pragma unroll
    for (int nt = 0; nt < 4; nt++)
      b[nt] = *reinterpret_cast<const short8v*>(Bs + (wcol + nt * 16 + l16) * 32 + quad * 8);
#pragma unroll
    for (int mt = 0; mt < 8; mt++)
#pragma unroll
      for (int nt = 0; nt < 4; nt++)
        acc[mt][nt] = __builtin_amdgcn_mfma_f32_16x16x32_bf16(a[mt], b[nt], acc[mt][nt], 0, 0, 0);
  }

  // epilogue: D row = quad*4+reg, col = lane&15
#pragma unroll
  for (int nt = 0; nt < 4; nt++) {
    int col = nbase + wcol + nt * 16 + l16;
    float bv = bias[col];
#pragma unroll
    for (int mt = 0; mt < 8; mt++) {
      int row = mbase + wrow + mt * 16 + quad * 4;
#pragma unroll
      for (int r = 0; r < 4; r++) {
        float v = acc[mt][nt][r] + bv;
        if (relu_mode) v = fmaxf(v, 0.f);
        size_t idx = (size_t)(row + r) * ldc + col;
        if (out_f32) ((float*)C)[idx] = v;
        else         ((short*)C)[idx] = f2b(v);
      }
    }
  }
}

// ---------------------------------------------------------------------------
// Pipelined split-K GEMM for grid-limited shapes (WO, FF2). 3-buffer LDS,
// counted vmcnt + T1 XCD swizzle. blockIdx.z selects a K-slice; partial sums
// atomicAdd into fp32 C (bias pre-initialized).
// ---------------------------------------------------------------------------
__global__ __launch_bounds__(256) void gemm_pipe(
    const bf16* __restrict__ A, const bf16* __restrict__ Bt,
    float* __restrict__ C, int K, int ldc, int k_len) {
  __shared__ __align__(16) bf16 As[3][128 * 32];
  __shared__ __align__(16) bf16 Bs[3][128 * 32];
  const int tid = threadIdx.x;
  const int w = tid >> 6, lane = tid & 63;
  const int quad = lane >> 4, l16 = lane & 15;
  const int wrow = (w >> 1) * 64, wcol = (w & 1) * 64;
  int bx, by, bz;
  xcd_swizzle(bx, by, bz);
  const int mbase = by * 128, nbase = bx * 128;
  const int c0 = w * 128 + lane;           // chunk ids c0 and c0+64
  const int row0 = c0 >> 2, p0 = c0 & 3;
  const int row1 = (c0 + 64) >> 2, p1 = (c0 + 64) & 3;
  const int kbase = bz * k_len;

  const bf16* ag0 = A + (size_t)(mbase + row0) * K + kbase + p0 * 8;
  const bf16* ag1 = A + (size_t)(mbase + row1) * K + kbase + p1 * 8;
  const bf16* bg0 = Bt + (size_t)(nbase + row0) * K + kbase + p0 * 8;
  const bf16* bg1 = Bt + (size_t)(nbase + row1) * K + kbase + p1 * 8;

  auto stage = [&](int t, int bi) {
    const int ko = t * 32;
    char* da = (char*)As + bi * 8192 + w * 2048;
    char* db = (char*)Bs + bi * 8192 + w * 2048;
    gload_lds16(ag0 + ko, da);
    gload_lds16(ag1 + ko, da + 1024);
    gload_lds16(bg0 + ko, db);
    gload_lds16(bg1 + ko, db + 1024);
  };

  float4v acc[4][4];
  for (int i = 0; i < 4; i++)
    for (int j = 0; j < 4; j++) acc[i][j] = (float4v){0.f, 0.f, 0.f, 0.f};

  const int KT = k_len >> 5;
  // prologue: tiles 0,1 in flight (8 outstanding per wave)
  stage(0, 0);
  stage(1, 1);

  for (int kt = 0; kt < KT; kt++) {
    const int pb = kt % 3;
    // drain tile kt's own 4 loads; tile kt+1's 4 may remain in flight
    if (kt + 1 < KT) asm volatile("s_waitcnt vmcnt(4)" ::: "memory");
    else             asm volatile("s_waitcnt vmcnt(0)" ::: "memory");
    __builtin_amdgcn_s_barrier();
    asm volatile("" ::: "memory");   // compiler fence: no LDS-op motion across barrier

    if (kt + 2 < KT) stage(kt + 2, (kt + 2) % 3);

    short8v a[4], b[4];
    for (int mt = 0; mt < 4; mt++)
      a[mt] = *reinterpret_cast<const short8v*>(&As[pb][(wrow + mt * 16 + l16) * 32 + quad * 8]);
    for (int nt = 0; nt < 4; nt++)
      b[nt] = *reinterpret_cast<const short8v*>(&Bs[pb][(wcol + nt * 16 + l16) * 32 + quad * 8]);
    for (int mt = 0; mt < 4; mt++)
      for (int nt = 0; nt < 4; nt++)
        acc[mt][nt] = __builtin_amdgcn_mfma_f32_16x16x32_bf16(a[mt], b[nt], acc[mt][nt], 0, 0, 0);
  }

  // epilogue: partial-sum atomicAdd (C pre-initialized with bias)
  for (int nt = 0; nt < 4; nt++) {
    int col = nbase + wcol + nt * 16 + l16;
    for (int mt = 0; mt < 4; mt++) {
      int row = mbase + wrow + mt * 16 + quad * 4;
      for (int r = 0; r < 4; r++)
        atomicAdd(&C[(size_t)(row + r) * ldc + col], acc[mt][nt][r]);
    }
  }
}

// C[row, 0..N) = bias[0..N), fp32. grid = rows, block 256, N = 1024.
__global__ __launch_bounds__(256) void bias_init(
    const float* __restrict__ bias, float* __restrict__ C) {
  int c = threadIdx.x * 4;
  float4 bv = *reinterpret_cast<const float4*>(bias + c);
  *reinterpret_cast<float4*>(C + (size_t)blockIdx.x * 1024 + c) = bv;
}

// ---------------------------------------------------------------------------
// Flash attention v10: v8 structure (32 q/wave, 512 blocks — round-10 proved
// the occupancy split only duplicates q-independent overhead) + KVBLK=64:
// each iteration stages/processes TWO 32-kv subtiles -> 32 iterations.
// Barriers halve, prefetch bookkeeping halves, loads get a 2x window.
// Subtile-1 pointers = subtile-0 + 6144 elems (32 kv rows = 2 qkv rows;
// local&1023 preserved so the flat offset is exact). Iteration stride 12288.
// Swizzles unchanged ((krow+32)&7 == krow&7; rr&7 == l16&7).
// ---------------------------------------------------------------------------
__global__ __launch_bounds__(256) void attn_kernel(
    const bf16* __restrict__ qkv, const int* __restrict__ mask,
    bf16* __restrict__ ao) {
  __shared__ __align__(16) short Vt[2][64 * 72];   // [buf][d][kv0..63], pitch 72
  __shared__ __align__(16) short Ks[2][64 * 64];   // [buf][kv][d], row-XOR-swizzled

  const int tid = threadIdx.x;
  const int w = tid >> 6, lane = tid & 63;
  const int quad = lane >> 4, l16 = lane & 15;
  const int bh = blockIdx.y, b = bh >> 4;
  const int row0 = bh * 128;                 // row base in qkv [4096,3072]
  const int qbase = blockIdx.x * 128 + w * 32;  // wave's 32 q rows
  const int kvp = tid & 15, dg = tid >> 4;   // V stager: kv rows 2kvp,2kvp+1; d 4dg..+3
  const int krow = tid >> 3, kc = tid & 7;   // K stager: rows krow & krow+32, chunk kc

  // Q fragments (B-operand of swapped QK^T); Q is pre-scaled by log2(e)/8
  short8v aq[2][2];
  for (int h = 0; h < 2; h++)
    for (int dh = 0; dh < 2; dh++) {
      int local = (qbase + h * 16 + l16) * 64 + dh * 32 + quad * 8;
      aq[h][dh] = *reinterpret_cast<const short8v*>(
          qkv + (size_t)(row0 + (local >> 10)) * 3072 + (local & 1023));
    }

  // K stage pointers (2 b128/thread cover the 64x64 tile)
  const bf16* pks0;
  {
    int local = krow * 64 + kc * 8;
    pks0 = qkv + (size_t)(row0 + (local >> 10)) * 3072 + (local & 1023) + 1024;
  }
  const bf16* pks1 = pks0 + 6144;
  // V stage pointers (2 kv rows x 4 d per thread, x2 subtiles)
  const bf16* pva;
  const bf16* pvb;
  {
    int la = (2 * kvp) * 64 + dg * 4;
    pva = qkv + (size_t)(row0 + (la >> 10)) * 3072 + (la & 1023) + 2048;
    int lb = (2 * kvp + 1) * 64 + dg * 4;
    pvb = qkv + (size_t)(row0 + (lb >> 10)) * 3072 + (lb & 1023) + 2048;
  }
  const bf16* pva2 = pva + 6144;
  const bf16* pvb2 = pvb + 6144;
  const int* pm = mask + b * 2048 + quad * 4;

  float4v o[2][4];
  for (int h = 0; h < 2; h++)
    for (int nt = 0; nt < 4; nt++) o[h][nt] = (float4v){0.f, 0.f, 0.f, 0.f};
  float4v lacc[2];
  lacc[0] = (float4v){0.f, 0.f, 0.f, 0.f};
  lacc[1] = (float4v){0.f, 0.f, 0.f, 0.f};
  short8v vone;
  for (int j = 0; j < 8; j++) vone[j] = (short)0x3F80;  // bf16 1.0 x8

  // prologue: load + stage tile 0 (64 kv rows)
  short8v kr0, kr1;
  short4v va, vb, va2, vb2;
  kr0 = *reinterpret_cast<const short8v*>(pks0);
  kr1 = *reinterpret_cast<const short8v*>(pks1);
  va  = *reinterpret_cast<const short4v*>(pva);
  vb  = *reinterpret_cast<const short4v*>(pvb);
  va2 = *reinterpret_cast<const short4v*>(pva2);
  vb2 = *reinterpret_cast<const short4v*>(pvb2);
  int4 mc0 = *reinterpret_cast<const int4*>(pm);
  int4 mc1 = *reinterpret_cast<const int4*>(pm + 16);
  int4 mc2 = *reinterpret_cast<const int4*>(pm + 32);
  int4 mc3 = *reinterpret_cast<const int4*>(pm + 48);
  pks0 += 12288; pks1 += 12288; pva += 12288; pvb += 12288;
  pva2 += 12288; pvb2 += 12288; pm += 64;
  {
    const int sw = (kc ^ (krow & 7)) << 3;
    *reinterpret_cast<short8v*>(&Ks[0][krow * 64 + sw]) = kr0;
    *reinterpret_cast<short8v*>(&Ks[0][(krow + 32) * 64 + sw]) = kr1;
    uint32_t* vt = reinterpret_cast<uint32_t*>(&Vt[0][0]);
    for (int i = 0; i < 4; i++) {
      vt[(dg * 4 + i) * 36 + kvp] =
          ((uint32_t)(uint16_t)vb[i] << 16) | (uint16_t)(uint16_t)va[i];
      vt[(dg * 4 + i) * 36 + 16 + kvp] =
          ((uint32_t)(uint16_t)vb2[i] << 16) | (uint16_t)(uint16_t)va2[i];
    }
  }
  __syncthreads();

  for (int it = 0; it < 32; it++) {
    const int pb = it & 1;
    short8v knr0, knr1;
    short4v vna, vnb, vna2, vnb2;
    int4 mn0, mn1, mn2, mn3;
    if (it < 31) {
      knr0 = *reinterpret_cast<const short8v*>(pks0);
      knr1 = *reinterpret_cast<const short8v*>(pks1);
      vna  = *reinterpret_cast<const short4v*>(pva);
      vnb  = *reinterpret_cast<const short4v*>(pvb);
      vna2 = *reinterpret_cast<const short4v*>(pva2);
      vnb2 = *reinterpret_cast<const short4v*>(pvb2);
      mn0 = *reinterpret_cast<const int4*>(pm);
      mn1 = *reinterpret_cast<const int4*>(pm + 16);
      mn2 = *reinterpret_cast<const int4*>(pm + 32);
      mn3 = *reinterpret_cast<const int4*>(pm + 48);
      pks0 += 12288; pks1 += 12288; pva += 12288; pvb += 12288;
      pva2 += 12288; pvb2 += 12288; pm += 64;
    }

#pragma unroll
    for (int sub = 0; sub < 2; sub++) {
      // K fragments from LDS (swizzled read: chunk (dh*4+quad) ^ (l16&7))
      short8v kc_[2][2];
      for (int s = 0; s < 2; s++)
        for (int dh = 0; dh < 2; dh++) {
          int rr = sub * 32 + s * 16 + l16;
          kc_[s][dh] = *reinterpret_cast<const short8v*>(
              &Ks[pb][rr * 64 + (((dh * 4 + quad) ^ (l16 & 7)) << 3)]);
        }

      float4v st[2][2];
      for (int s = 0; s < 2; s++)
        for (int h = 0; h < 2; h++) {
          float4v t = (float4v){0.f, 0.f, 0.f, 0.f};
          t = __builtin_amdgcn_mfma_f32_16x16x32_bf16(kc_[s][0], aq[h][0], t, 0, 0, 0);
          t = __builtin_amdgcn_mfma_f32_16x16x32_bf16(kc_[s][1], aq[h][1], t, 0, 0, 0);
          st[s][h] = t;
        }

      // softmax numerator + in-register P-fragment assembly (no LDS)
      short8v pf[2];
      for (int h = 0; h < 2; h++) {
        float ev[2][4];
        for (int s = 0; s < 2; s++) {
          int4 mv = sub ? (s ? mc3 : mc2) : (s ? mc1 : mc0);
          int mm[4] = {mv.x, mv.y, mv.z, mv.w};
          for (int r = 0; r < 4; r++) {
            float y = st[s][h][r];                    // already exp2-arg units
            y = (mm[r] == 0) ? -1.4427e-12f : y;      // faithful mask semantics
            ev[s][r] = __builtin_amdgcn_exp2f(y);
          }
        }
        uint32_t a0, a1, b0, b1;
        asm("v_cvt_pk_bf16_f32 %0, %1, %2" : "=v"(a0) : "v"(ev[0][0]), "v"(ev[0][1]));
        asm("v_cvt_pk_bf16_f32 %0, %1, %2" : "=v"(a1) : "v"(ev[0][2]), "v"(ev[0][3]));
        asm("v_cvt_pk_bf16_f32 %0, %1, %2" : "=v"(b0) : "v"(ev[1][0]), "v"(ev[1][1]));
        asm("v_cvt_pk_bf16_f32 %0, %1, %2" : "=v"(b1) : "v"(ev[1][2]), "v"(ev[1][3]));
        // halves: lanes<32 hold A-family (s=0), >=32 B-family (s=1)
        asm("v_permlane32_swap_b32 %0, %1" : "+v"(b0), "+v"(a0));
        asm("v_permlane16_swap_b32 %0, %1" : "+v"(b0), "+v"(a0));
        asm("v_permlane32_swap_b32 %0, %1" : "+v"(b1), "+v"(a1));
        asm("v_permlane16_swap_b32 %0, %1" : "+v"(b1), "+v"(a1));
        union { short8v s8; uint32_t u[4]; } pfu;
        pfu.u[0] = a0; pfu.u[1] = a1; pfu.u[2] = b0; pfu.u[3] = b1;
        pf[h] = pfu.s8;
      }

      for (int h = 0; h < 2; h++)
        lacc[h] = __builtin_amdgcn_mfma_f32_16x16x32_bf16(pf[h], vone, lacc[h], 0, 0, 0);
      for (int nt = 0; nt < 4; nt++) {
        short8v bv = *reinterpret_cast<const short8v*>(
            &Vt[pb][(nt * 16 + l16) * 72 + sub * 32 + quad * 8]);
        for (int h = 0; h < 2; h++)
          o[h][nt] = __builtin_amdgcn_mfma_f32_16x16x32_bf16(pf[h], bv, o[h][nt], 0, 0, 0);
      }
    }

    if (it < 31) {
      const int sw = (kc ^ (krow & 7)) << 3;
      *reinterpret_cast<short8v*>(&Ks[1 - pb][krow * 64 + sw]) = knr0;
      *reinterpret_cast<short8v*>(&Ks[1 - pb][(krow + 32) * 64 + sw]) = knr1;
      uint32_t* vt = reinterpret_cast<uint32_t*>(&Vt[1 - pb][0]);
      for (int i = 0; i < 4; i++) {
        vt[(dg * 4 + i) * 36 + kvp] =
            ((uint32_t)(uint16_t)vnb[i] << 16) | (uint16_t)(uint16_t)vna[i];
        vt[(dg * 4 + i) * 36 + 16 + kvp] =
            ((uint32_t)(uint16_t)vnb2[i] << 16) | (uint16_t)(uint16_t)vna2[i];
      }
      mc0 = mn0; mc1 = mn1; mc2 = mn2; mc3 = mn3;
    }
    __syncthreads();
  }

  // lacc[h][r] = rowsum(P) for q row quad*4+r (all 16 cols identical)
  for (int h = 0; h < 2; h++)
    for (int r = 0; r < 4; r++) {
      float linv = 1.0f / lacc[h][r];
      int qg = qbase + h * 16 + quad * 4 + r;
      for (int nt = 0; nt < 4; nt++) {
        int d = nt * 16 + l16;
        ao[(size_t)bh * 131072 + (size_t)qg * 64 + d] = __float2bfloat16(o[h][nt][r] * linv);
      }
    }
}

// ---------------------------------------------------------------------------
// out = LN(a + xres); unbiased std (ddof=1), /(std + 1e-12). One block / row.
// ---------------------------------------------------------------------------
__global__ __launch_bounds__(256) void ln_resid(
    const void* __restrict__ a, const void* __restrict__ xres,
    const float* __restrict__ gamma, const float* __restrict__ beta,
    void* __restrict__ out, int a_f32, int x_f32, int out_f32) {
  __shared__ float red[8];
  const int row = blockIdx.x, tid = threadIdx.x;
  const int w = tid >> 6, lane = tid & 63;
  const size_t base = (size_t)row * 1024;
  float v[4]; float sum = 0.f, ss = 0.f;
  for (int i = 0; i < 4; i++) {
    int c = tid + i * 256;
    float av = a_f32 ? ((const float*)a)[base + c] : b2f(((const short*)a)[base + c]);
    float xv = x_f32 ? ((const float*)xres)[base + c] : b2f(((const short*)xres)[base + c]);
    v[i] = av + xv;
    sum += v[i]; ss += v[i] * v[i];
  }
  for (int off = 1; off < 64; off <<= 1) {
    sum += __shfl_xor(sum, off);
    ss  += __shfl_xor(ss, off);
  }
  if (lane == 0) { red[w * 2] = sum; red[w * 2 + 1] = ss; }
  __syncthreads();
  sum = red[0] + red[2] + red[4] + red[6];
  ss  = red[1] + red[3] + red[5] + red[7];
  float mean = sum * (1.0f / 1024.0f);
  float var = (ss - 1024.0f * mean * mean) * (1.0f / 1023.0f);
  var = fmaxf(var, 0.f);
  float rden = 1.0f / (sqrtf(var) + 1e-12f);
  for (int i = 0; i < 4; i++) {
    int c = tid + i * 256;
    float y = gamma[c] * ((v[i] - mean) * rden) + beta[c];
    if (out_f32) ((float*)out)[base + c] = y;
    else         ((short*)out)[base + c] = f2b(y);
  }
}

// out(bf16)[c*R + r] = in(f32)[r*C + c] * scale; R,C % 32 == 0.
__global__ __launch_bounds__(256) void transpose_k(
    const float* __restrict__ in, bf16* __restrict__ out, int R, int C,
    float scale) {
  __shared__ short t[32][33];
  const int tx = threadIdx.x, ty = threadIdx.y;
  const int cb = blockIdx.x * 32, rb = blockIdx.y * 32;
  for (int j = 0; j < 4; j++)
    t[ty + j * 8][tx] = f2b(in[(size_t)(rb + ty + j * 8) * C + cb + tx] * scale);
  __syncthreads();
  for (int j = 0; j < 4; j++)
    ((short*)out)[(size_t)(cb + ty + j * 8) * R + rb + tx] = t[tx][ty + j * 8];
}

// q-bias scaled by log2(e)/8 to match the pre-scaled Q projection.
__global__ __launch_bounds__(256) void concat3(
    const float* __restrict__ a, const float* __restrict__ b,
    const float* __restrict__ c, float* __restrict__ out) {
  int i = blockIdx.x * 256 + threadIdx.x;  // grid 12 -> 3072
  float v;
  if (i < 1024)       v = a[i] * 0.18033688f;
  else if (i < 2048)  v = b[i - 1024];
  else                v = c[i - 2048];
  out[i] = v;
}

__global__ __launch_bounds__(256) void cast_f32_bf16(
    const float* __restrict__ in, bf16* __restrict__ out) {
  int i0 = (blockIdx.x * 256 + threadIdx.x) * 4;
  float4 f = *reinterpret_cast<const float4*>(in + i0);
  short* o = (short*)out + i0;
  o[0] = f2b(f.x); o[1] = f2b(f.y); o[2] = f2b(f.z); o[3] = f2b(f.w);
}

// ---------------------------------------------------------------------------
extern "C" void kernel_launch(void* const* d_in, const int* in_sizes, int n_in,
                              void* d_out, int out_size, void* d_ws, size_t ws_size,
                              hipStream_t stream) {
  (void)in_sizes; (void)n_in; (void)out_size; (void)ws_size;
  const float* x    = (const float*)d_in[0];
  const int*   mask = (const int*)d_in[1];
  const float* wq_w = (const float*)d_in[2];
  const float* wq_b = (const float*)d_in[3];
  const float* wk_w = (const float*)d_in[4];
  const float* wk_b = (const float*)d_in[5];
  const float* wv_w = (const float*)d_in[6];
  const float* wv_b = (const float*)d_in[7];
  const float* wo_w = (const float*)d_in[8];
  const float* wo_b = (const float*)d_in[9];
  const float* g1   = (const float*)d_in[10];
  const float* be1  = (const float*)d_in[11];
  const float* f1w  = (const float*)d_in[12];
  const float* f1b  = (const float*)d_in[13];
  const float* f2w  = (const float*)d_in[14];
  const float* f2b_ = (const float*)d_in[15];
  const float* g2   = (const float*)d_in[16];
  const float* be2  = (const float*)d_in[17];
  float* out = (float*)d_out;
  char* ws = (char*)d_ws;

  // ws layout (peak 48 MiB, time-shared):
  //  [0,24M)   QKV (ph2-3) -> PROJ fp32 [0,16M) (ph4-5) -> H [0,32M) (ph6-7)
  //  [24M,32M) Xbf (ph1-2) -> AO (ph3-4)
  //  [32M,40M) X1  (ph5-8)
  //  [40M,48M) WT  (transposed weights, per-phase)  + BQKV fp32 tail
  bf16*  QKV  = (bf16*)(ws + 0);
  bf16*  Xbf  = (bf16*)(ws + 25165824);
  bf16*  AO   = (bf16*)(ws + 25165824);
  float* PROJ = (float*)(ws + 0);
  bf16*  H    = (bf16*)(ws + 0);
  bf16*  X1   = (bf16*)(ws + 33554432);
  bf16*  WT   = (bf16*)(ws + 41943040);
  float* BQKV = (float*)(ws + 48234496);

  const float QSCALE = 0.18033688f;  // (1/sqrt(64)) * log2(e)

  dim3 tb(32, 8);
  // phase 1: casts + QKV weights (wq pre-scaled for exp2-direct softmax)
  cast_f32_bf16<<<dim3(4096), dim3(256), 0, stream>>>(x, Xbf);
  transpose_k<<<dim3(32, 32), tb, 0, stream>>>(wq_w, WT, 1024, 1024, QSCALE);
  transpose_k<<<dim3(32, 32), tb, 0, stream>>>(wk_w, WT + 1024 * 1024, 1024, 1024, 1.0f);
  transpose_k<<<dim3(32, 32), tb, 0, stream>>>(wv_w, WT + 2 * 1024 * 1024, 1024, 1024, 1.0f);
  concat3<<<dim3(12), dim3(256), 0, stream>>>(wq_b, wk_b, wv_b, BQKV);
  // phase 2: fused QKV projection [4096,1024]@[3072,1024]^T -> bf16 (256² tile)
  gemm_bt256<<<dim3(12, 16), dim3(512), 0, stream>>>(Xbf, WT, BQKV, QKV, 1024, 3072, 0, 0);
  // phase 3: attention (512 blocks: 16 q-blocks x 32 bh, KVBLK=64)
  attn_kernel<<<dim3(16, 32), dim3(256), 0, stream>>>(QKV, mask, AO);
  // phase 4: output projection — counted-vmcnt pipeline, split-K=2, fp32
  // atomic into PROJ
  transpose_k<<<dim3(32, 32), tb, 0, stream>>>(wo_w, WT, 1024, 1024, 1.0f);
  bias_init<<<dim3(4096), dim3(256), 0, stream>>>(wo_b, PROJ);
  gemm_pipe<<<dim3(8, 32, 2), dim3(256), 0, stream>>>(AO, WT, PROJ, 1024, 1024, 512);
  // phase 5: LN1 (a = PROJ fp32, xres = original fp32 x)
  ln_resid<<<dim3(4096), dim3(256), 0, stream>>>(PROJ, x, g1, be1, X1, 1, 1, 0);
  // phase 6: FFN up (256² tile, 256 blocks = 1/CU, 8 waves)
  transpose_k<<<dim3(128, 32), tb, 0, stream>>>(f1w, WT, 1024, 4096, 1.0f);
  gemm_bt256<<<dim3(16, 16), dim3(512), 0, stream>>>(X1, WT, f1b, H, 1024, 4096, 1, 0);
  // phase 7: FFN down — counted-vmcnt pipeline, split-K=2, fp32 atomic
  // straight into d_out
  transpose_k<<<dim3(32, 128), tb, 0, stream>>>(f2w, WT, 4096, 1024, 1.0f);
  bias_init<<<dim3(4096), dim3(256), 0, stream>>>(f2b_, out);
  gemm_pipe<<<dim3(8, 32, 2), dim3(256), 0, stream>>>(H, WT, out, 4096, 1024, 2048);
  // phase 8: LN2 in-place on d_out (fp32 a, bf16 xres, fp32 out)
  ln_resid<<<dim3(4096), dim3(256), 0, stream>>>(out, X1, g2, be2, out, 1, 0, 1);
}

// Round 12
// 432.574 us; speedup vs baseline: 1.0976x; 1.0217x over previous
//
#include <hip/hip_runtime.h>
#include <hip/hip_bf16.h>
#include <cstdint>
#include <cstddef>

using bf16 = __hip_bfloat16;
typedef __attribute__((ext_vector_type(8))) short short8v;   // MFMA A/B frag: 8 bf16
typedef __attribute__((ext_vector_type(4))) short short4v;   // 4 bf16 (b64 load/store)
typedef __attribute__((ext_vector_type(4))) float float4v;   // MFMA C/D frag

__device__ inline float b2f(short s) {
  union { float f; uint32_t u; } z; z.u = ((uint32_t)(uint16_t)s) << 16; return z.f;
}
__device__ inline short f2b(float f) {
  bf16 h = __float2bfloat16(f);
  return *reinterpret_cast<short*>(&h);
}

typedef const __attribute__((address_space(1))) uint32_t* gas1p;
typedef __attribute__((address_space(3))) uint32_t* las3p;
__device__ inline void gload_lds16(const void* g, void* l) {
  __builtin_amdgcn_global_load_lds((gas1p)g, (las3p)l, 16, 0, 0);
}

// T1 XCD swizzle (gemm_pipe only). Round-11 PMC confirmed it works here:
// FETCH dropped 135 MB -> 32.8 MB (compulsory traffic).
__device__ inline void xcd_swizzle(int& bx, int& by, int& bz) {
  const int gx = gridDim.x, gy = gridDim.y;
  const int nwg = gx * gy * gridDim.z;
  const int wgid = blockIdx.x + gx * (blockIdx.y + gy * blockIdx.z);
  const int swz = (wgid & 7) * (nwg >> 3) + (wgid >> 3);
  bx = swz % gx;
  by = (swz / gx) % gy;
  bz = swz / (gx * gy);
}

// ---------------------------------------------------------------------------
// 256x256-tile GEMM, 8 waves (2x4), per-wave output 128x64, BK=32, 2-phase.
// (round 9: pulled FF1/QKV out of the top-5 — per-FLOP traffic halved vs 128².)
// ---------------------------------------------------------------------------
__global__ __launch_bounds__(512, 2) void gemm_bt256(
    const bf16* __restrict__ A, const bf16* __restrict__ Bt,
    const float* __restrict__ bias, void* __restrict__ C,
    int K, int ldc, int relu_mode, int out_f32) {
  __shared__ __align__(16) bf16 As[256 * 32];
  __shared__ __align__(16) bf16 Bs[256 * 32];
  const int tid = threadIdx.x;             // 0..511
  const int w = tid >> 6, lane = tid & 63;
  const int quad = lane >> 4, l16 = lane & 15;
  const int wrow = (w >> 2) * 128, wcol = (w & 3) * 64;   // 2x4 wave grid
  const int mbase = blockIdx.y * 256, nbase = blockIdx.x * 256;
  const int row0 = tid >> 2, p0 = tid & 3;
  const int row1 = (tid + 512) >> 2, p1 = (tid + 512) & 3;

  float4v acc[8][4];
#pragma unroll
  for (int i = 0; i < 8; i++)
#pragma unroll
    for (int j = 0; j < 4; j++) acc[i][j] = (float4v){0.f, 0.f, 0.f, 0.f};

  for (int k0 = 0; k0 < K; k0 += 32) {
    __syncthreads();  // prev iter's ds_reads done before restage
    gload_lds16(A + (size_t)(mbase + row0) * K + k0 + p0 * 8, (char*)As + w * 1024);
    gload_lds16(A + (size_t)(mbase + row1) * K + k0 + p1 * 8, (char*)As + 8192 + w * 1024);
    gload_lds16(Bt + (size_t)(nbase + row0) * K + k0 + p0 * 8, (char*)Bs + w * 1024);
    gload_lds16(Bt + (size_t)(nbase + row1) * K + k0 + p1 * 8, (char*)Bs + 8192 + w * 1024);
    __syncthreads();  // vmcnt drained -> tiles valid

    short8v a[8], b[4];
#pragma unroll
    for (int mt = 0; mt < 8; mt++)
      a[mt] = *reinterpret_cast<const short8v*>(As + (wrow + mt * 16 + l16) * 32 + quad * 8);
#pragma unroll
    for (int nt = 0; nt < 4; nt++)
      b[nt] = *reinterpret_cast<const short8v*>(Bs + (wcol + nt * 16 + l16) * 32 + quad * 8);
#pragma unroll
    for (int mt = 0; mt < 8; mt++)
#pragma unroll
      for (int nt = 0; nt < 4; nt++)
        acc[mt][nt] = __builtin_amdgcn_mfma_f32_16x16x32_bf16(a[mt], b[nt], acc[mt][nt], 0, 0, 0);
  }

  // epilogue: D row = quad*4+reg, col = lane&15
#pragma unroll
  for (int nt = 0; nt < 4; nt++) {
    int col = nbase + wcol + nt * 16 + l16;
    float bv = bias[col];
#pragma unroll
    for (int mt = 0; mt < 8; mt++) {
      int row = mbase + wrow + mt * 16 + quad * 4;
#pragma unroll
      for (int r = 0; r < 4; r++) {
        float v = acc[mt][nt][r] + bv;
        if (relu_mode) v = fmaxf(v, 0.f);
        size_t idx = (size_t)(row + r) * ldc + col;
        if (out_f32) ((float*)C)[idx] = v;
        else         ((short*)C)[idx] = f2b(v);
      }
    }
  }
}

// ---------------------------------------------------------------------------
// Pipelined split-K GEMM for grid-limited shapes (WO, FF2). v4 (round 12):
// BK=64 per barrier — the lever that worked for attn in round 11 (KVBLK
// 32->64). Each iteration stages & computes a 64-col tile as TWO proven
// BK=32 halves (byte-identical chunk map / fragment layout per half).
// Barriers per block halve; each tile's 8 gload_lds get a full 2x compute
// window (~1400 cyc) before the drain. LDS 64 KB -> still 2 blocks/CU.
// + T1 XCD swizzle (FETCH at compulsory 32.8 MB since round 11).
// blockIdx.z selects a K-slice; partial sums atomicAdd into fp32 C.
// ---------------------------------------------------------------------------
__global__ __launch_bounds__(256) void gemm_pipe(
    const bf16* __restrict__ A, const bf16* __restrict__ Bt,
    float* __restrict__ C, int K, int ldc, int k_len) {
  __shared__ __align__(16) bf16 As[2][2][128 * 32];  // [buf][half][tile]
  __shared__ __align__(16) bf16 Bs[2][2][128 * 32];
  const int tid = threadIdx.x;
  const int w = tid >> 6, lane = tid & 63;
  const int quad = lane >> 4, l16 = lane & 15;
  const int wrow = (w >> 1) * 64, wcol = (w & 1) * 64;
  int bx, by, bz;
  xcd_swizzle(bx, by, bz);
  const int mbase = by * 128, nbase = bx * 128;
  const int c0 = w * 128 + lane;           // chunk ids c0 and c0+64
  const int row0 = c0 >> 2, p0 = c0 & 3;
  const int row1 = (c0 + 64) >> 2, p1 = (c0 + 64) & 3;
  const int kbase = bz * k_len;

  const bf16* ag0 = A + (size_t)(mbase + row0) * K + kbase + p0 * 8;
  const bf16* ag1 = A + (size_t)(mbase + row1) * K + kbase + p1 * 8;
  const bf16* bg0 = Bt + (size_t)(nbase + row0) * K + kbase + p0 * 8;
  const bf16* bg1 = Bt + (size_t)(nbase + row1) * K + kbase + p1 * 8;

  // stage 64-col tile t64 into buffer bi (two BK=32 halves)
  auto stage = [&](int t64, int bi) {
    const int ko = t64 * 64;
#pragma unroll
    for (int h = 0; h < 2; h++) {
      char* da = (char*)As + (size_t)(bi * 2 + h) * 8192 + w * 2048;
      char* db = (char*)Bs + (size_t)(bi * 2 + h) * 8192 + w * 2048;
      gload_lds16(ag0 + ko + h * 32, da);
      gload_lds16(ag1 + ko + h * 32, da + 1024);
      gload_lds16(bg0 + ko + h * 32, db);
      gload_lds16(bg1 + ko + h * 32, db + 1024);
    }
  };

  float4v acc[4][4];
  for (int i = 0; i < 4; i++)
    for (int j = 0; j < 4; j++) acc[i][j] = (float4v){0.f, 0.f, 0.f, 0.f};

  const int KT2 = k_len >> 6;
  // prologue: tile 0 -> buf 0
  stage(0, 0);
  __syncthreads();

  for (int kt = 0; kt < KT2; kt++) {
    const int pb = kt & 1;
    if (kt + 1 < KT2) stage(kt + 1, 1 - pb);  // issued early, drained at barrier

#pragma unroll
    for (int h = 0; h < 2; h++) {
      const bf16* Ah = &As[pb][h][0];
      const bf16* Bh = &Bs[pb][h][0];
      short8v a[4], b[4];
      for (int mt = 0; mt < 4; mt++)
        a[mt] = *reinterpret_cast<const short8v*>(Ah + (wrow + mt * 16 + l16) * 32 + quad * 8);
      for (int nt = 0; nt < 4; nt++)
        b[nt] = *reinterpret_cast<const short8v*>(Bh + (wcol + nt * 16 + l16) * 32 + quad * 8);
      for (int mt = 0; mt < 4; mt++)
        for (int nt = 0; nt < 4; nt++)
          acc[mt][nt] = __builtin_amdgcn_mfma_f32_16x16x32_bf16(a[mt], b[nt], acc[mt][nt], 0, 0, 0);
    }

    __syncthreads();  // drains vmcnt (next tile valid) + lgkm (reads done)
  }

  // epilogue: partial-sum atomicAdd (C pre-initialized with bias)
  for (int nt = 0; nt < 4; nt++) {
    int col = nbase + wcol + nt * 16 + l16;
    for (int mt = 0; mt < 4; mt++) {
      int row = mbase + wrow + mt * 16 + quad * 4;
      for (int r = 0; r < 4; r++)
        atomicAdd(&C[(size_t)(row + r) * ldc + col], acc[mt][nt][r]);
    }
  }
}

// C[row, 0..N) = bias[0..N), fp32. grid = rows, block 256, N = 1024.
__global__ __launch_bounds__(256) void bias_init(
    const float* __restrict__ bias, float* __restrict__ C) {
  int c = threadIdx.x * 4;
  float4 bv = *reinterpret_cast<const float4*>(bias + c);
  *reinterpret_cast<float4*>(C + (size_t)blockIdx.x * 1024 + c) = bv;
}

// ---------------------------------------------------------------------------
// Flash attention v10 (round 11, unchanged): 32 q/wave, 512 blocks, KVBLK=64
// (two 32-kv subtiles per barrier) — 32 iterations.
// ---------------------------------------------------------------------------
__global__ __launch_bounds__(256) void attn_kernel(
    const bf16* __restrict__ qkv, const int* __restrict__ mask,
    bf16* __restrict__ ao) {
  __shared__ __align__(16) short Vt[2][64 * 72];   // [buf][d][kv0..63], pitch 72
  __shared__ __align__(16) short Ks[2][64 * 64];   // [buf][kv][d], row-XOR-swizzled

  const int tid = threadIdx.x;
  const int w = tid >> 6, lane = tid & 63;
  const int quad = lane >> 4, l16 = lane & 15;
  const int bh = blockIdx.y, b = bh >> 4;
  const int row0 = bh * 128;                 // row base in qkv [4096,3072]
  const int qbase = blockIdx.x * 128 + w * 32;  // wave's 32 q rows
  const int kvp = tid & 15, dg = tid >> 4;   // V stager: kv rows 2kvp,2kvp+1; d 4dg..+3
  const int krow = tid >> 3, kc = tid & 7;   // K stager: rows krow & krow+32, chunk kc

  // Q fragments (B-operand of swapped QK^T); Q is pre-scaled by log2(e)/8
  short8v aq[2][2];
  for (int h = 0; h < 2; h++)
    for (int dh = 0; dh < 2; dh++) {
      int local = (qbase + h * 16 + l16) * 64 + dh * 32 + quad * 8;
      aq[h][dh] = *reinterpret_cast<const short8v*>(
          qkv + (size_t)(row0 + (local >> 10)) * 3072 + (local & 1023));
    }

  // K stage pointers (2 b128/thread cover the 64x64 tile)
  const bf16* pks0;
  {
    int local = krow * 64 + kc * 8;
    pks0 = qkv + (size_t)(row0 + (local >> 10)) * 3072 + (local & 1023) + 1024;
  }
  const bf16* pks1 = pks0 + 6144;
  // V stage pointers (2 kv rows x 4 d per thread, x2 subtiles)
  const bf16* pva;
  const bf16* pvb;
  {
    int la = (2 * kvp) * 64 + dg * 4;
    pva = qkv + (size_t)(row0 + (la >> 10)) * 3072 + (la & 1023) + 2048;
    int lb = (2 * kvp + 1) * 64 + dg * 4;
    pvb = qkv + (size_t)(row0 + (lb >> 10)) * 3072 + (lb & 1023) + 2048;
  }
  const bf16* pva2 = pva + 6144;
  const bf16* pvb2 = pvb + 6144;
  const int* pm = mask + b * 2048 + quad * 4;

  float4v o[2][4];
  for (int h = 0; h < 2; h++)
    for (int nt = 0; nt < 4; nt++) o[h][nt] = (float4v){0.f, 0.f, 0.f, 0.f};
  float4v lacc[2];
  lacc[0] = (float4v){0.f, 0.f, 0.f, 0.f};
  lacc[1] = (float4v){0.f, 0.f, 0.f, 0.f};
  short8v vone;
  for (int j = 0; j < 8; j++) vone[j] = (short)0x3F80;  // bf16 1.0 x8

  // prologue: load + stage tile 0 (64 kv rows)
  short8v kr0, kr1;
  short4v va, vb, va2, vb2;
  kr0 = *reinterpret_cast<const short8v*>(pks0);
  kr1 = *reinterpret_cast<const short8v*>(pks1);
  va  = *reinterpret_cast<const short4v*>(pva);
  vb  = *reinterpret_cast<const short4v*>(pvb);
  va2 = *reinterpret_cast<const short4v*>(pva2);
  vb2 = *reinterpret_cast<const short4v*>(pvb2);
  int4 mc0 = *reinterpret_cast<const int4*>(pm);
  int4 mc1 = *reinterpret_cast<const int4*>(pm + 16);
  int4 mc2 = *reinterpret_cast<const int4*>(pm + 32);
  int4 mc3 = *reinterpret_cast<const int4*>(pm + 48);
  pks0 += 12288; pks1 += 12288; pva += 12288; pvb += 12288;
  pva2 += 12288; pvb2 += 12288; pm += 64;
  {
    const int sw = (kc ^ (krow & 7)) << 3;
    *reinterpret_cast<short8v*>(&Ks[0][krow * 64 + sw]) = kr0;
    *reinterpret_cast<short8v*>(&Ks[0][(krow + 32) * 64 + sw]) = kr1;
    uint32_t* vt = reinterpret_cast<uint32_t*>(&Vt[0][0]);
    for (int i = 0; i < 4; i++) {
      vt[(dg * 4 + i) * 36 + kvp] =
          ((uint32_t)(uint16_t)vb[i] << 16) | (uint16_t)(uint16_t)va[i];
      vt[(dg * 4 + i) * 36 + 16 + kvp] =
          ((uint32_t)(uint16_t)vb2[i] << 16) | (uint16_t)(uint16_t)va2[i];
    }
  }
  __syncthreads();

  for (int it = 0; it < 32; it++) {
    const int pb = it & 1;
    short8v knr0, knr1;
    short4v vna, vnb, vna2, vnb2;
    int4 mn0, mn1, mn2, mn3;
    if (it < 31) {
      knr0 = *reinterpret_cast<const short8v*>(pks0);
      knr1 = *reinterpret_cast<const short8v*>(pks1);
      vna  = *reinterpret_cast<const short4v*>(pva);
      vnb  = *reinterpret_cast<const short4v*>(pvb);
      vna2 = *reinterpret_cast<const short4v*>(pva2);
      vnb2 = *reinterpret_cast<const short4v*>(pvb2);
      mn0 = *reinterpret_cast<const int4*>(pm);
      mn1 = *reinterpret_cast<const int4*>(pm + 16);
      mn2 = *reinterpret_cast<const int4*>(pm + 32);
      mn3 = *reinterpret_cast<const int4*>(pm + 48);
      pks0 += 12288; pks1 += 12288; pva += 12288; pvb += 12288;
      pva2 += 12288; pvb2 += 12288; pm += 64;
    }

#pragma unroll
    for (int sub = 0; sub < 2; sub++) {
      // K fragments from LDS (swizzled read: chunk (dh*4+quad) ^ (l16&7))
      short8v kc_[2][2];
      for (int s = 0; s < 2; s++)
        for (int dh = 0; dh < 2; dh++) {
          int rr = sub * 32 + s * 16 + l16;
          kc_[s][dh] = *reinterpret_cast<const short8v*>(
              &Ks[pb][rr * 64 + (((dh * 4 + quad) ^ (l16 & 7)) << 3)]);
        }

      float4v st[2][2];
      for (int s = 0; s < 2; s++)
        for (int h = 0; h < 2; h++) {
          float4v t = (float4v){0.f, 0.f, 0.f, 0.f};
          t = __builtin_amdgcn_mfma_f32_16x16x32_bf16(kc_[s][0], aq[h][0], t, 0, 0, 0);
          t = __builtin_amdgcn_mfma_f32_16x16x32_bf16(kc_[s][1], aq[h][1], t, 0, 0, 0);
          st[s][h] = t;
        }

      // softmax numerator + in-register P-fragment assembly (no LDS)
      short8v pf[2];
      for (int h = 0; h < 2; h++) {
        float ev[2][4];
        for (int s = 0; s < 2; s++) {
          int4 mv = sub ? (s ? mc3 : mc2) : (s ? mc1 : mc0);
          int mm[4] = {mv.x, mv.y, mv.z, mv.w};
          for (int r = 0; r < 4; r++) {
            float y = st[s][h][r];                    // already exp2-arg units
            y = (mm[r] == 0) ? -1.4427e-12f : y;      // faithful mask semantics
            ev[s][r] = __builtin_amdgcn_exp2f(y);
          }
        }
        uint32_t a0, a1, b0, b1;
        asm("v_cvt_pk_bf16_f32 %0, %1, %2" : "=v"(a0) : "v"(ev[0][0]), "v"(ev[0][1]));
        asm("v_cvt_pk_bf16_f32 %0, %1, %2" : "=v"(a1) : "v"(ev[0][2]), "v"(ev[0][3]));
        asm("v_cvt_pk_bf16_f32 %0, %1, %2" : "=v"(b0) : "v"(ev[1][0]), "v"(ev[1][1]));
        asm("v_cvt_pk_bf16_f32 %0, %1, %2" : "=v"(b1) : "v"(ev[1][2]), "v"(ev[1][3]));
        // halves: lanes<32 hold A-family (s=0), >=32 B-family (s=1)
        asm("v_permlane32_swap_b32 %0, %1" : "+v"(b0), "+v"(a0));
        asm("v_permlane16_swap_b32 %0, %1" : "+v"(b0), "+v"(a0));
        asm("v_permlane32_swap_b32 %0, %1" : "+v"(b1), "+v"(a1));
        asm("v_permlane16_swap_b32 %0, %1" : "+v"(b1), "+v"(a1));
        union { short8v s8; uint32_t u[4]; } pfu;
        pfu.u[0] = a0; pfu.u[1] = a1; pfu.u[2] = b0; pfu.u[3] = b1;
        pf[h] = pfu.s8;
      }

      for (int h = 0; h < 2; h++)
        lacc[h] = __builtin_amdgcn_mfma_f32_16x16x32_bf16(pf[h], vone, lacc[h], 0, 0, 0);
      for (int nt = 0; nt < 4; nt++) {
        short8v bv = *reinterpret_cast<const short8v*>(
            &Vt[pb][(nt * 16 + l16) * 72 + sub * 32 + quad * 8]);
        for (int h = 0; h < 2; h++)
          o[h][nt] = __builtin_amdgcn_mfma_f32_16x16x32_bf16(pf[h], bv, o[h][nt], 0, 0, 0);
      }
    }

    if (it < 31) {
      const int sw = (kc ^ (krow & 7)) << 3;
      *reinterpret_cast<short8v*>(&Ks[1 - pb][krow * 64 + sw]) = knr0;
      *reinterpret_cast<short8v*>(&Ks[1 - pb][(krow + 32) * 64 + sw]) = knr1;
      uint32_t* vt = reinterpret_cast<uint32_t*>(&Vt[1 - pb][0]);
      for (int i = 0; i < 4; i++) {
        vt[(dg * 4 + i) * 36 + kvp] =
            ((uint32_t)(uint16_t)vnb[i] << 16) | (uint16_t)(uint16_t)vna[i];
        vt[(dg * 4 + i) * 36 + 16 + kvp] =
            ((uint32_t)(uint16_t)vnb2[i] << 16) | (uint16_t)(uint16_t)vna2[i];
      }
      mc0 = mn0; mc1 = mn1; mc2 = mn2; mc3 = mn3;
    }
    __syncthreads();
  }

  // lacc[h][r] = rowsum(P) for q row quad*4+r (all 16 cols identical)
  for (int h = 0; h < 2; h++)
    for (int r = 0; r < 4; r++) {
      float linv = 1.0f / lacc[h][r];
      int qg = qbase + h * 16 + quad * 4 + r;
      for (int nt = 0; nt < 4; nt++) {
        int d = nt * 16 + l16;
        ao[(size_t)bh * 131072 + (size_t)qg * 64 + d] = __float2bfloat16(o[h][nt][r] * linv);
      }
    }
}

// ---------------------------------------------------------------------------
// out = LN(a + xres); unbiased std (ddof=1), /(std + 1e-12). One block / row.
// ---------------------------------------------------------------------------
__global__ __launch_bounds__(256) void ln_resid(
    const void* __restrict__ a, const void* __restrict__ xres,
    const float* __restrict__ gamma, const float* __restrict__ beta,
    void* __restrict__ out, int a_f32, int x_f32, int out_f32) {
  __shared__ float red[8];
  const int row = blockIdx.x, tid = threadIdx.x;
  const int w = tid >> 6, lane = tid & 63;
  const size_t base = (size_t)row * 1024;
  float v[4]; float sum = 0.f, ss = 0.f;
  for (int i = 0; i < 4; i++) {
    int c = tid + i * 256;
    float av = a_f32 ? ((const float*)a)[base + c] : b2f(((const short*)a)[base + c]);
    float xv = x_f32 ? ((const float*)xres)[base + c] : b2f(((const short*)xres)[base + c]);
    v[i] = av + xv;
    sum += v[i]; ss += v[i] * v[i];
  }
  for (int off = 1; off < 64; off <<= 1) {
    sum += __shfl_xor(sum, off);
    ss  += __shfl_xor(ss, off);
  }
  if (lane == 0) { red[w * 2] = sum; red[w * 2 + 1] = ss; }
  __syncthreads();
  sum = red[0] + red[2] + red[4] + red[6];
  ss  = red[1] + red[3] + red[5] + red[7];
  float mean = sum * (1.0f / 1024.0f);
  float var = (ss - 1024.0f * mean * mean) * (1.0f / 1023.0f);
  var = fmaxf(var, 0.f);
  float rden = 1.0f / (sqrtf(var) + 1e-12f);
  for (int i = 0; i < 4; i++) {
    int c = tid + i * 256;
    float y = gamma[c] * ((v[i] - mean) * rden) + beta[c];
    if (out_f32) ((float*)out)[base + c] = y;
    else         ((short*)out)[base + c] = f2b(y);
  }
}

// out(bf16)[c*R + r] = in(f32)[r*C + c] * scale; R,C % 32 == 0.
__global__ __launch_bounds__(256) void transpose_k(
    const float* __restrict__ in, bf16* __restrict__ out, int R, int C,
    float scale) {
  __shared__ short t[32][33];
  const int tx = threadIdx.x, ty = threadIdx.y;
  const int cb = blockIdx.x * 32, rb = blockIdx.y * 32;
  for (int j = 0; j < 4; j++)
    t[ty + j * 8][tx] = f2b(in[(size_t)(rb + ty + j * 8) * C + cb + tx] * scale);
  __syncthreads();
  for (int j = 0; j < 4; j++)
    ((short*)out)[(size_t)(cb + ty + j * 8) * R + rb + tx] = t[tx][ty + j * 8];
}

// q-bias scaled by log2(e)/8 to match the pre-scaled Q projection.
__global__ __launch_bounds__(256) void concat3(
    const float* __restrict__ a, const float* __restrict__ b,
    const float* __restrict__ c, float* __restrict__ out) {
  int i = blockIdx.x * 256 + threadIdx.x;  // grid 12 -> 3072
  float v;
  if (i < 1024)       v = a[i] * 0.18033688f;
  else if (i < 2048)  v = b[i - 1024];
  else                v = c[i - 2048];
  out[i] = v;
}

__global__ __launch_bounds__(256) void cast_f32_bf16(
    const float* __restrict__ in, bf16* __restrict__ out) {
  int i0 = (blockIdx.x * 256 + threadIdx.x) * 4;
  float4 f = *reinterpret_cast<const float4*>(in + i0);
  short* o = (short*)out + i0;
  o[0] = f2b(f.x); o[1] = f2b(f.y); o[2] = f2b(f.z); o[3] = f2b(f.w);
}

// ---------------------------------------------------------------------------
extern "C" void kernel_launch(void* const* d_in, const int* in_sizes, int n_in,
                              void* d_out, int out_size, void* d_ws, size_t ws_size,
                              hipStream_t stream) {
  (void)in_sizes; (void)n_in; (void)out_size; (void)ws_size;
  const float* x    = (const float*)d_in[0];
  const int*   mask = (const int*)d_in[1];
  const float* wq_w = (const float*)d_in[2];
  const float* wq_b = (const float*)d_in[3];
  const float* wk_w = (const float*)d_in[4];
  const float* wk_b = (const float*)d_in[5];
  const float* wv_w = (const float*)d_in[6];
  const float* wv_b = (const float*)d_in[7];
  const float* wo_w = (const float*)d_in[8];
  const float* wo_b = (const float*)d_in[9];
  const float* g1   = (const float*)d_in[10];
  const float* be1  = (const float*)d_in[11];
  const float* f1w  = (const float*)d_in[12];
  const float* f1b  = (const float*)d_in[13];
  const float* f2w  = (const float*)d_in[14];
  const float* f2b_ = (const float*)d_in[15];
  const float* g2   = (const float*)d_in[16];
  const float* be2  = (const float*)d_in[17];
  float* out = (float*)d_out;
  char* ws = (char*)d_ws;

  // ws layout (peak 48 MiB, time-shared):
  //  [0,24M)   QKV (ph2-3) -> PROJ fp32 [0,16M) (ph4-5) -> H [0,32M) (ph6-7)
  //  [24M,32M) Xbf (ph1-2) -> AO (ph3-4)
  //  [32M,40M) X1  (ph5-8)
  //  [40M,48M) WT  (transposed weights, per-phase)  + BQKV fp32 tail
  bf16*  QKV  = (bf16*)(ws + 0);
  bf16*  Xbf  = (bf16*)(ws + 25165824);
  bf16*  AO   = (bf16*)(ws + 25165824);
  float* PROJ = (float*)(ws + 0);
  bf16*  H    = (bf16*)(ws + 0);
  bf16*  X1   = (bf16*)(ws + 33554432);
  bf16*  WT   = (bf16*)(ws + 41943040);
  float* BQKV = (float*)(ws + 48234496);

  const float QSCALE = 0.18033688f;  // (1/sqrt(64)) * log2(e)

  dim3 tb(32, 8);
  // phase 1: casts + QKV weights (wq pre-scaled for exp2-direct softmax)
  cast_f32_bf16<<<dim3(4096), dim3(256), 0, stream>>>(x, Xbf);
  transpose_k<<<dim3(32, 32), tb, 0, stream>>>(wq_w, WT, 1024, 1024, QSCALE);
  transpose_k<<<dim3(32, 32), tb, 0, stream>>>(wk_w, WT + 1024 * 1024, 1024, 1024, 1.0f);
  transpose_k<<<dim3(32, 32), tb, 0, stream>>>(wv_w, WT + 2 * 1024 * 1024, 1024, 1024, 1.0f);
  concat3<<<dim3(12), dim3(256), 0, stream>>>(wq_b, wk_b, wv_b, BQKV);
  // phase 2: fused QKV projection [4096,1024]@[3072,1024]^T -> bf16 (256² tile)
  gemm_bt256<<<dim3(12, 16), dim3(512), 0, stream>>>(Xbf, WT, BQKV, QKV, 1024, 3072, 0, 0);
  // phase 3: attention (512 blocks: 16 q-blocks x 32 bh, KVBLK=64)
  attn_kernel<<<dim3(16, 32), dim3(256), 0, stream>>>(QKV, mask, AO);
  // phase 4: output projection — BK=64 pipeline, split-K=2, fp32 atomic into PROJ
  transpose_k<<<dim3(32, 32), tb, 0, stream>>>(wo_w, WT, 1024, 1024, 1.0f);
  bias_init<<<dim3(4096), dim3(256), 0, stream>>>(wo_b, PROJ);
  gemm_pipe<<<dim3(8, 32, 2), dim3(256), 0, stream>>>(AO, WT, PROJ, 1024, 1024, 512);
  // phase 5: LN1 (a = PROJ fp32, xres = original fp32 x)
  ln_resid<<<dim3(4096), dim3(256), 0, stream>>>(PROJ, x, g1, be1, X1, 1, 1, 0);
  // phase 6: FFN up (256² tile, 256 blocks = 1/CU, 8 waves)
  transpose_k<<<dim3(128, 32), tb, 0, stream>>>(f1w, WT, 1024, 4096, 1.0f);
  gemm_bt256<<<dim3(16, 16), dim3(512), 0, stream>>>(X1, WT, f1b, H, 1024, 4096, 1, 0);
  // phase 7: FFN down — BK=64 pipeline, split-K=2, fp32 atomic straight into d_out
  transpose_k<<<dim3(32, 128), tb, 0, stream>>>(f2w, WT, 4096, 1024, 1.0f);
  bias_init<<<dim3(4096), dim3(256), 0, stream>>>(f2b_, out);
  gemm_pipe<<<dim3(8, 32, 2), dim3(256), 0, stream>>>(H, WT, out, 4096, 1024, 2048);
  // phase 8: LN2 in-place on d_out (fp32 a, bf16 xres, fp32 out)
  ln_resid<<<dim3(4096), dim3(256), 0, stream>>>(out, X1, g2, be2, out, 1, 0, 1);
}

// Round 13
// 421.595 us; speedup vs baseline: 1.1262x; 1.0260x over previous
//
#include <hip/hip_runtime.h>
#include <hip/hip_bf16.h>
#include <cstdint>
#include <cstddef>

using bf16 = __hip_bfloat16;
typedef __attribute__((ext_vector_type(8))) short short8v;   // MFMA A/B frag: 8 bf16
typedef __attribute__((ext_vector_type(4))) short short4v;   // 4 bf16 (b64 load/store)
typedef __attribute__((ext_vector_type(4))) float float4v;   // MFMA C/D frag

__device__ inline float b2f(short s) {
  union { float f; uint32_t u; } z; z.u = ((uint32_t)(uint16_t)s) << 16; return z.f;
}
__device__ inline short f2b(float f) {
  bf16 h = __float2bfloat16(f);
  return *reinterpret_cast<short*>(&h);
}

typedef const __attribute__((address_space(1))) uint32_t* gas1p;
typedef __attribute__((address_space(3))) uint32_t* las3p;
__device__ inline void gload_lds16(const void* g, void* l) {
  __builtin_amdgcn_global_load_lds((gas1p)g, (las3p)l, 16, 0, 0);
}

// T1 XCD swizzle (gemm_pipe only). Round-11 PMC confirmed: FETCH dropped
// 135 MB -> 32.8 MB (compulsory traffic).
__device__ inline void xcd_swizzle(int& bx, int& by, int& bz) {
  const int gx = gridDim.x, gy = gridDim.y;
  const int nwg = gx * gy * gridDim.z;
  const int wgid = blockIdx.x + gx * (blockIdx.y + gy * blockIdx.z);
  const int swz = (wgid & 7) * (nwg >> 3) + (wgid >> 3);
  bx = swz % gx;
  by = (swz / gx) % gy;
  bz = swz / (gx * gy);
}

// ---------------------------------------------------------------------------
// 256x256-tile GEMM, 8 waves (2x4), per-wave output 128x64. v2 (round 13):
// the round-12 gemm_pipe v4 structure ported to the 256² tile — round-12 PMC
// showed the old 2-barrier single-buffer loop at 1 block/CU was 80% stalled
// on the per-iter vmcnt(0) drain (6450 cyc/iter vs ~600 of work, Mfma 11.5).
// Now: double-buffered LDS, BK=64 as two proven BK=32 halves, stage next
// 64-col tile at iter top, ONE barrier per iter. 16 iters for K=1024; each
// tile's 8 gload_lds get the full current-iter compute window (~1200 cyc)
// before the drain. LDS 128 KB (fits at the already-1-block/CU occupancy).
// Chunk map per half byte-identical to the proven one. C = A@Bt^T + bias.
// ---------------------------------------------------------------------------
__global__ __launch_bounds__(512, 2) void gemm_bt256(
    const bf16* __restrict__ A, const bf16* __restrict__ Bt,
    const float* __restrict__ bias, void* __restrict__ C,
    int K, int ldc, int relu_mode, int out_f32) {
  __shared__ __align__(16) bf16 As[2][2][256 * 32];  // [buf][half][tile]
  __shared__ __align__(16) bf16 Bs[2][2][256 * 32];
  const int tid = threadIdx.x;             // 0..511
  const int w = tid >> 6, lane = tid & 63;
  const int quad = lane >> 4, l16 = lane & 15;
  const int wrow = (w >> 2) * 128, wcol = (w & 3) * 64;   // 2x4 wave grid
  const int mbase = blockIdx.y * 256, nbase = blockIdx.x * 256;
  // staging (per 32-col half): chunk c -> tile row c>>2, part c&3, LDS byte
  // c*16 within the half. thread t handles chunks t and t+512.
  const int row0 = tid >> 2, p0 = tid & 3;
  const int row1 = (tid + 512) >> 2, p1 = (tid + 512) & 3;

  const bf16* ag0 = A + (size_t)(mbase + row0) * K + p0 * 8;
  const bf16* ag1 = A + (size_t)(mbase + row1) * K + p1 * 8;
  const bf16* bg0 = Bt + (size_t)(nbase + row0) * K + p0 * 8;
  const bf16* bg1 = Bt + (size_t)(nbase + row1) * K + p1 * 8;

  // stage 64-col tile t64 into buffer bi (two BK=32 halves; 16 KB regions)
  auto stage = [&](int t64, int bi) {
    const int ko = t64 * 64;
#pragma unroll
    for (int h = 0; h < 2; h++) {
      char* da = (char*)As + (size_t)(bi * 2 + h) * 16384 + w * 1024;
      char* db = (char*)Bs + (size_t)(bi * 2 + h) * 16384 + w * 1024;
      gload_lds16(ag0 + ko + h * 32, da);
      gload_lds16(ag1 + ko + h * 32, da + 8192);
      gload_lds16(bg0 + ko + h * 32, db);
      gload_lds16(bg1 + ko + h * 32, db + 8192);
    }
  };

  float4v acc[8][4];
#pragma unroll
  for (int i = 0; i < 8; i++)
#pragma unroll
    for (int j = 0; j < 4; j++) acc[i][j] = (float4v){0.f, 0.f, 0.f, 0.f};

  const int KT2 = K >> 6;
  // prologue: tile 0 -> buf 0
  stage(0, 0);
  __syncthreads();

  for (int kt = 0; kt < KT2; kt++) {
    const int pb = kt & 1;
    if (kt + 1 < KT2) stage(kt + 1, 1 - pb);  // issued early, drained at barrier

#pragma unroll
    for (int h = 0; h < 2; h++) {
      const bf16* Ah = &As[pb][h][0];
      const bf16* Bh = &Bs[pb][h][0];
      short8v a[8], b[4];
#pragma unroll
      for (int mt = 0; mt < 8; mt++)
        a[mt] = *reinterpret_cast<const short8v*>(Ah + (wrow + mt * 16 + l16) * 32 + quad * 8);
#pragma unroll
      for (int nt = 0; nt < 4; nt++)
        b[nt] = *reinterpret_cast<const short8v*>(Bh + (wcol + nt * 16 + l16) * 32 + quad * 8);
#pragma unroll
      for (int mt = 0; mt < 8; mt++)
#pragma unroll
        for (int nt = 0; nt < 4; nt++)
          acc[mt][nt] = __builtin_amdgcn_mfma_f32_16x16x32_bf16(a[mt], b[nt], acc[mt][nt], 0, 0, 0);
    }

    __syncthreads();  // drains vmcnt (next tile valid) + lgkm (reads done)
  }

  // epilogue: D row = quad*4+reg, col = lane&15
#pragma unroll
  for (int nt = 0; nt < 4; nt++) {
    int col = nbase + wcol + nt * 16 + l16;
    float bv = bias[col];
#pragma unroll
    for (int mt = 0; mt < 8; mt++) {
      int row = mbase + wrow + mt * 16 + quad * 4;
#pragma unroll
      for (int r = 0; r < 4; r++) {
        float v = acc[mt][nt][r] + bv;
        if (relu_mode) v = fmaxf(v, 0.f);
        size_t idx = (size_t)(row + r) * ldc + col;
        if (out_f32) ((float*)C)[idx] = v;
        else         ((short*)C)[idx] = f2b(v);
      }
    }
  }
}

// ---------------------------------------------------------------------------
// Pipelined split-K GEMM for grid-limited shapes (WO, FF2). v4: BK=64 per
// barrier as two BK=32 halves, double-buffered, one barrier/iter, + T1 XCD
// swizzle. blockIdx.z selects a K-slice; partial sums atomicAdd into fp32 C.
// ---------------------------------------------------------------------------
__global__ __launch_bounds__(256) void gemm_pipe(
    const bf16* __restrict__ A, const bf16* __restrict__ Bt,
    float* __restrict__ C, int K, int ldc, int k_len) {
  __shared__ __align__(16) bf16 As[2][2][128 * 32];  // [buf][half][tile]
  __shared__ __align__(16) bf16 Bs[2][2][128 * 32];
  const int tid = threadIdx.x;
  const int w = tid >> 6, lane = tid & 63;
  const int quad = lane >> 4, l16 = lane & 15;
  const int wrow = (w >> 1) * 64, wcol = (w & 1) * 64;
  int bx, by, bz;
  xcd_swizzle(bx, by, bz);
  const int mbase = by * 128, nbase = bx * 128;
  const int c0 = w * 128 + lane;           // chunk ids c0 and c0+64
  const int row0 = c0 >> 2, p0 = c0 & 3;
  const int row1 = (c0 + 64) >> 2, p1 = (c0 + 64) & 3;
  const int kbase = bz * k_len;

  const bf16* ag0 = A + (size_t)(mbase + row0) * K + kbase + p0 * 8;
  const bf16* ag1 = A + (size_t)(mbase + row1) * K + kbase + p1 * 8;
  const bf16* bg0 = Bt + (size_t)(nbase + row0) * K + kbase + p0 * 8;
  const bf16* bg1 = Bt + (size_t)(nbase + row1) * K + kbase + p1 * 8;

  // stage 64-col tile t64 into buffer bi (two BK=32 halves)
  auto stage = [&](int t64, int bi) {
    const int ko = t64 * 64;
#pragma unroll
    for (int h = 0; h < 2; h++) {
      char* da = (char*)As + (size_t)(bi * 2 + h) * 8192 + w * 2048;
      char* db = (char*)Bs + (size_t)(bi * 2 + h) * 8192 + w * 2048;
      gload_lds16(ag0 + ko + h * 32, da);
      gload_lds16(ag1 + ko + h * 32, da + 1024);
      gload_lds16(bg0 + ko + h * 32, db);
      gload_lds16(bg1 + ko + h * 32, db + 1024);
    }
  };

  float4v acc[4][4];
  for (int i = 0; i < 4; i++)
    for (int j = 0; j < 4; j++) acc[i][j] = (float4v){0.f, 0.f, 0.f, 0.f};

  const int KT2 = k_len >> 6;
  // prologue: tile 0 -> buf 0
  stage(0, 0);
  __syncthreads();

  for (int kt = 0; kt < KT2; kt++) {
    const int pb = kt & 1;
    if (kt + 1 < KT2) stage(kt + 1, 1 - pb);  // issued early, drained at barrier

#pragma unroll
    for (int h = 0; h < 2; h++) {
      const bf16* Ah = &As[pb][h][0];
      const bf16* Bh = &Bs[pb][h][0];
      short8v a[4], b[4];
      for (int mt = 0; mt < 4; mt++)
        a[mt] = *reinterpret_cast<const short8v*>(Ah + (wrow + mt * 16 + l16) * 32 + quad * 8);
      for (int nt = 0; nt < 4; nt++)
        b[nt] = *reinterpret_cast<const short8v*>(Bh + (wcol + nt * 16 + l16) * 32 + quad * 8);
      for (int mt = 0; mt < 4; mt++)
        for (int nt = 0; nt < 4; nt++)
          acc[mt][nt] = __builtin_amdgcn_mfma_f32_16x16x32_bf16(a[mt], b[nt], acc[mt][nt], 0, 0, 0);
    }

    __syncthreads();  // drains vmcnt (next tile valid) + lgkm (reads done)
  }

  // epilogue: partial-sum atomicAdd (C pre-initialized with bias)
  for (int nt = 0; nt < 4; nt++) {
    int col = nbase + wcol + nt * 16 + l16;
    for (int mt = 0; mt < 4; mt++) {
      int row = mbase + wrow + mt * 16 + quad * 4;
      for (int r = 0; r < 4; r++)
        atomicAdd(&C[(size_t)(row + r) * ldc + col], acc[mt][nt][r]);
    }
  }
}

// C[row, 0..N) = bias[0..N), fp32. grid = rows, block 256, N = 1024.
__global__ __launch_bounds__(256) void bias_init(
    const float* __restrict__ bias, float* __restrict__ C) {
  int c = threadIdx.x * 4;
  float4 bv = *reinterpret_cast<const float4*>(bias + c);
  *reinterpret_cast<float4*>(C + (size_t)blockIdx.x * 1024 + c) = bv;
}

// ---------------------------------------------------------------------------
// Flash attention v10 (round 11, unchanged): 32 q/wave, 512 blocks, KVBLK=64
// (two 32-kv subtiles per barrier) — 32 iterations.
// ---------------------------------------------------------------------------
__global__ __launch_bounds__(256) void attn_kernel(
    const bf16* __restrict__ qkv, const int* __restrict__ mask,
    bf16* __restrict__ ao) {
  __shared__ __align__(16) short Vt[2][64 * 72];   // [buf][d][kv0..63], pitch 72
  __shared__ __align__(16) short Ks[2][64 * 64];   // [buf][kv][d], row-XOR-swizzled

  const int tid = threadIdx.x;
  const int w = tid >> 6, lane = tid & 63;
  const int quad = lane >> 4, l16 = lane & 15;
  const int bh = blockIdx.y, b = bh >> 4;
  const int row0 = bh * 128;                 // row base in qkv [4096,3072]
  const int qbase = blockIdx.x * 128 + w * 32;  // wave's 32 q rows
  const int kvp = tid & 15, dg = tid >> 4;   // V stager: kv rows 2kvp,2kvp+1; d 4dg..+3
  const int krow = tid >> 3, kc = tid & 7;   // K stager: rows krow & krow+32, chunk kc

  // Q fragments (B-operand of swapped QK^T); Q is pre-scaled by log2(e)/8
  short8v aq[2][2];
  for (int h = 0; h < 2; h++)
    for (int dh = 0; dh < 2; dh++) {
      int local = (qbase + h * 16 + l16) * 64 + dh * 32 + quad * 8;
      aq[h][dh] = *reinterpret_cast<const short8v*>(
          qkv + (size_t)(row0 + (local >> 10)) * 3072 + (local & 1023));
    }

  // K stage pointers (2 b128/thread cover the 64x64 tile)
  const bf16* pks0;
  {
    int local = krow * 64 + kc * 8;
    pks0 = qkv + (size_t)(row0 + (local >> 10)) * 3072 + (local & 1023) + 1024;
  }
  const bf16* pks1 = pks0 + 6144;
  // V stage pointers (2 kv rows x 4 d per thread, x2 subtiles)
  const bf16* pva;
  const bf16* pvb;
  {
    int la = (2 * kvp) * 64 + dg * 4;
    pva = qkv + (size_t)(row0 + (la >> 10)) * 3072 + (la & 1023) + 2048;
    int lb = (2 * kvp + 1) * 64 + dg * 4;
    pvb = qkv + (size_t)(row0 + (lb >> 10)) * 3072 + (lb & 1023) + 2048;
  }
  const bf16* pva2 = pva + 6144;
  const bf16* pvb2 = pvb + 6144;
  const int* pm = mask + b * 2048 + quad * 4;

  float4v o[2][4];
  for (int h = 0; h < 2; h++)
    for (int nt = 0; nt < 4; nt++) o[h][nt] = (float4v){0.f, 0.f, 0.f, 0.f};
  float4v lacc[2];
  lacc[0] = (float4v){0.f, 0.f, 0.f, 0.f};
  lacc[1] = (float4v){0.f, 0.f, 0.f, 0.f};
  short8v vone;
  for (int j = 0; j < 8; j++) vone[j] = (short)0x3F80;  // bf16 1.0 x8

  // prologue: load + stage tile 0 (64 kv rows)
  short8v kr0, kr1;
  short4v va, vb, va2, vb2;
  kr0 = *reinterpret_cast<const short8v*>(pks0);
  kr1 = *reinterpret_cast<const short8v*>(pks1);
  va  = *reinterpret_cast<const short4v*>(pva);
  vb  = *reinterpret_cast<const short4v*>(pvb);
  va2 = *reinterpret_cast<const short4v*>(pva2);
  vb2 = *reinterpret_cast<const short4v*>(pvb2);
  int4 mc0 = *reinterpret_cast<const int4*>(pm);
  int4 mc1 = *reinterpret_cast<const int4*>(pm + 16);
  int4 mc2 = *reinterpret_cast<const int4*>(pm + 32);
  int4 mc3 = *reinterpret_cast<const int4*>(pm + 48);
  pks0 += 12288; pks1 += 12288; pva += 12288; pvb += 12288;
  pva2 += 12288; pvb2 += 12288; pm += 64;
  {
    const int sw = (kc ^ (krow & 7)) << 3;
    *reinterpret_cast<short8v*>(&Ks[0][krow * 64 + sw]) = kr0;
    *reinterpret_cast<short8v*>(&Ks[0][(krow + 32) * 64 + sw]) = kr1;
    uint32_t* vt = reinterpret_cast<uint32_t*>(&Vt[0][0]);
    for (int i = 0; i < 4; i++) {
      vt[(dg * 4 + i) * 36 + kvp] =
          ((uint32_t)(uint16_t)vb[i] << 16) | (uint16_t)(uint16_t)va[i];
      vt[(dg * 4 + i) * 36 + 16 + kvp] =
          ((uint32_t)(uint16_t)vb2[i] << 16) | (uint16_t)(uint16_t)va2[i];
    }
  }
  __syncthreads();

  for (int it = 0; it < 32; it++) {
    const int pb = it & 1;
    short8v knr0, knr1;
    short4v vna, vnb, vna2, vnb2;
    int4 mn0, mn1, mn2, mn3;
    if (it < 31) {
      knr0 = *reinterpret_cast<const short8v*>(pks0);
      knr1 = *reinterpret_cast<const short8v*>(pks1);
      vna  = *reinterpret_cast<const short4v*>(pva);
      vnb  = *reinterpret_cast<const short4v*>(pvb);
      vna2 = *reinterpret_cast<const short4v*>(pva2);
      vnb2 = *reinterpret_cast<const short4v*>(pvb2);
      mn0 = *reinterpret_cast<const int4*>(pm);
      mn1 = *reinterpret_cast<const int4*>(pm + 16);
      mn2 = *reinterpret_cast<const int4*>(pm + 32);
      mn3 = *reinterpret_cast<const int4*>(pm + 48);
      pks0 += 12288; pks1 += 12288; pva += 12288; pvb += 12288;
      pva2 += 12288; pvb2 += 12288; pm += 64;
    }

#pragma unroll
    for (int sub = 0; sub < 2; sub++) {
      // K fragments from LDS (swizzled read: chunk (dh*4+quad) ^ (l16&7))
      short8v kc_[2][2];
      for (int s = 0; s < 2; s++)
        for (int dh = 0; dh < 2; dh++) {
          int rr = sub * 32 + s * 16 + l16;
          kc_[s][dh] = *reinterpret_cast<const short8v*>(
              &Ks[pb][rr * 64 + (((dh * 4 + quad) ^ (l16 & 7)) << 3)]);
        }

      float4v st[2][2];
      for (int s = 0; s < 2; s++)
        for (int h = 0; h < 2; h++) {
          float4v t = (float4v){0.f, 0.f, 0.f, 0.f};
          t = __builtin_amdgcn_mfma_f32_16x16x32_bf16(kc_[s][0], aq[h][0], t, 0, 0, 0);
          t = __builtin_amdgcn_mfma_f32_16x16x32_bf16(kc_[s][1], aq[h][1], t, 0, 0, 0);
          st[s][h] = t;
        }

      // softmax numerator + in-register P-fragment assembly (no LDS)
      short8v pf[2];
      for (int h = 0; h < 2; h++) {
        float ev[2][4];
        for (int s = 0; s < 2; s++) {
          int4 mv = sub ? (s ? mc3 : mc2) : (s ? mc1 : mc0);
          int mm[4] = {mv.x, mv.y, mv.z, mv.w};
          for (int r = 0; r < 4; r++) {
            float y = st[s][h][r];                    // already exp2-arg units
            y = (mm[r] == 0) ? -1.4427e-12f : y;      // faithful mask semantics
            ev[s][r] = __builtin_amdgcn_exp2f(y);
          }
        }
        uint32_t a0, a1, b0, b1;
        asm("v_cvt_pk_bf16_f32 %0, %1, %2" : "=v"(a0) : "v"(ev[0][0]), "v"(ev[0][1]));
        asm("v_cvt_pk_bf16_f32 %0, %1, %2" : "=v"(a1) : "v"(ev[0][2]), "v"(ev[0][3]));
        asm("v_cvt_pk_bf16_f32 %0, %1, %2" : "=v"(b0) : "v"(ev[1][0]), "v"(ev[1][1]));
        asm("v_cvt_pk_bf16_f32 %0, %1, %2" : "=v"(b1) : "v"(ev[1][2]), "v"(ev[1][3]));
        // halves: lanes<32 hold A-family (s=0), >=32 B-family (s=1)
        asm("v_permlane32_swap_b32 %0, %1" : "+v"(b0), "+v"(a0));
        asm("v_permlane16_swap_b32 %0, %1" : "+v"(b0), "+v"(a0));
        asm("v_permlane32_swap_b32 %0, %1" : "+v"(b1), "+v"(a1));
        asm("v_permlane16_swap_b32 %0, %1" : "+v"(b1), "+v"(a1));
        union { short8v s8; uint32_t u[4]; } pfu;
        pfu.u[0] = a0; pfu.u[1] = a1; pfu.u[2] = b0; pfu.u[3] = b1;
        pf[h] = pfu.s8;
      }

      for (int h = 0; h < 2; h++)
        lacc[h] = __builtin_amdgcn_mfma_f32_16x16x32_bf16(pf[h], vone, lacc[h], 0, 0, 0);
      for (int nt = 0; nt < 4; nt++) {
        short8v bv = *reinterpret_cast<const short8v*>(
            &Vt[pb][(nt * 16 + l16) * 72 + sub * 32 + quad * 8]);
        for (int h = 0; h < 2; h++)
          o[h][nt] = __builtin_amdgcn_mfma_f32_16x16x32_bf16(pf[h], bv, o[h][nt], 0, 0, 0);
      }
    }

    if (it < 31) {
      const int sw = (kc ^ (krow & 7)) << 3;
      *reinterpret_cast<short8v*>(&Ks[1 - pb][krow * 64 + sw]) = knr0;
      *reinterpret_cast<short8v*>(&Ks[1 - pb][(krow + 32) * 64 + sw]) = knr1;
      uint32_t* vt = reinterpret_cast<uint32_t*>(&Vt[1 - pb][0]);
      for (int i = 0; i < 4; i++) {
        vt[(dg * 4 + i) * 36 + kvp] =
            ((uint32_t)(uint16_t)vnb[i] << 16) | (uint16_t)(uint16_t)vna[i];
        vt[(dg * 4 + i) * 36 + 16 + kvp] =
            ((uint32_t)(uint16_t)vnb2[i] << 16) | (uint16_t)(uint16_t)vna2[i];
      }
      mc0 = mn0; mc1 = mn1; mc2 = mn2; mc3 = mn3;
    }
    __syncthreads();
  }

  // lacc[h][r] = rowsum(P) for q row quad*4+r (all 16 cols identical)
  for (int h = 0; h < 2; h++)
    for (int r = 0; r < 4; r++) {
      float linv = 1.0f / lacc[h][r];
      int qg = qbase + h * 16 + quad * 4 + r;
      for (int nt = 0; nt < 4; nt++) {
        int d = nt * 16 + l16;
        ao[(size_t)bh * 131072 + (size_t)qg * 64 + d] = __float2bfloat16(o[h][nt][r] * linv);
      }
    }
}

// ---------------------------------------------------------------------------
// out = LN(a + xres); unbiased std (ddof=1), /(std + 1e-12). One block / row.
// ---------------------------------------------------------------------------
__global__ __launch_bounds__(256) void ln_resid(
    const void* __restrict__ a, const void* __restrict__ xres,
    const float* __restrict__ gamma, const float* __restrict__ beta,
    void* __restrict__ out, int a_f32, int x_f32, int out_f32) {
  __shared__ float red[8];
  const int row = blockIdx.x, tid = threadIdx.x;
  const int w = tid >> 6, lane = tid & 63;
  const size_t base = (size_t)row * 1024;
  float v[4]; float sum = 0.f, ss = 0.f;
  for (int i = 0; i < 4; i++) {
    int c = tid + i * 256;
    float av = a_f32 ? ((const float*)a)[base + c] : b2f(((const short*)a)[base + c]);
    float xv = x_f32 ? ((const float*)xres)[base + c] : b2f(((const short*)xres)[base + c]);
    v[i] = av + xv;
    sum += v[i]; ss += v[i] * v[i];
  }
  for (int off = 1; off < 64; off <<= 1) {
    sum += __shfl_xor(sum, off);
    ss  += __shfl_xor(ss, off);
  }
  if (lane == 0) { red[w * 2] = sum; red[w * 2 + 1] = ss; }
  __syncthreads();
  sum = red[0] + red[2] + red[4] + red[6];
  ss  = red[1] + red[3] + red[5] + red[7];
  float mean = sum * (1.0f / 1024.0f);
  float var = (ss - 1024.0f * mean * mean) * (1.0f / 1023.0f);
  var = fmaxf(var, 0.f);
  float rden = 1.0f / (sqrtf(var) + 1e-12f);
  for (int i = 0; i < 4; i++) {
    int c = tid + i * 256;
    float y = gamma[c] * ((v[i] - mean) * rden) + beta[c];
    if (out_f32) ((float*)out)[base + c] = y;
    else         ((short*)out)[base + c] = f2b(y);
  }
}

// out(bf16)[c*R + r] = in(f32)[r*C + c] * scale; R,C % 32 == 0.
__global__ __launch_bounds__(256) void transpose_k(
    const float* __restrict__ in, bf16* __restrict__ out, int R, int C,
    float scale) {
  __shared__ short t[32][33];
  const int tx = threadIdx.x, ty = threadIdx.y;
  const int cb = blockIdx.x * 32, rb = blockIdx.y * 32;
  for (int j = 0; j < 4; j++)
    t[ty + j * 8][tx] = f2b(in[(size_t)(rb + ty + j * 8) * C + cb + tx] * scale);
  __syncthreads();
  for (int j = 0; j < 4; j++)
    ((short*)out)[(size_t)(cb + ty + j * 8) * R + rb + tx] = t[tx][ty + j * 8];
}

// q-bias scaled by log2(e)/8 to match the pre-scaled Q projection.
__global__ __launch_bounds__(256) void concat3(
    const float* __restrict__ a, const float* __restrict__ b,
    const float* __restrict__ c, float* __restrict__ out) {
  int i = blockIdx.x * 256 + threadIdx.x;  // grid 12 -> 3072
  float v;
  if (i < 1024)       v = a[i] * 0.18033688f;
  else if (i < 2048)  v = b[i - 1024];
  else                v = c[i - 2048];
  out[i] = v;
}

__global__ __launch_bounds__(256) void cast_f32_bf16(
    const float* __restrict__ in, bf16* __restrict__ out) {
  int i0 = (blockIdx.x * 256 + threadIdx.x) * 4;
  float4 f = *reinterpret_cast<const float4*>(in + i0);
  short* o = (short*)out + i0;
  o[0] = f2b(f.x); o[1] = f2b(f.y); o[2] = f2b(f.z); o[3] = f2b(f.w);
}

// ---------------------------------------------------------------------------
extern "C" void kernel_launch(void* const* d_in, const int* in_sizes, int n_in,
                              void* d_out, int out_size, void* d_ws, size_t ws_size,
                              hipStream_t stream) {
  (void)in_sizes; (void)n_in; (void)out_size; (void)ws_size;
  const float* x    = (const float*)d_in[0];
  const int*   mask = (const int*)d_in[1];
  const float* wq_w = (const float*)d_in[2];
  const float* wq_b = (const float*)d_in[3];
  const float* wk_w = (const float*)d_in[4];
  const float* wk_b = (const float*)d_in[5];
  const float* wv_w = (const float*)d_in[6];
  const float* wv_b = (const float*)d_in[7];
  const float* wo_w = (const float*)d_in[8];
  const float* wo_b = (const float*)d_in[9];
  const float* g1   = (const float*)d_in[10];
  const float* be1  = (const float*)d_in[11];
  const float* f1w  = (const float*)d_in[12];
  const float* f1b  = (const float*)d_in[13];
  const float* f2w  = (const float*)d_in[14];
  const float* f2b_ = (const float*)d_in[15];
  const float* g2   = (const float*)d_in[16];
  const float* be2  = (const float*)d_in[17];
  float* out = (float*)d_out;
  char* ws = (char*)d_ws;

  // ws layout (peak 48 MiB, time-shared):
  //  [0,24M)   QKV (ph2-3) -> PROJ fp32 [0,16M) (ph4-5) -> H [0,32M) (ph6-7)
  //  [24M,32M) Xbf (ph1-2) -> AO (ph3-4)
  //  [32M,40M) X1  (ph5-8)
  //  [40M,48M) WT  (transposed weights, per-phase)  + BQKV fp32 tail
  bf16*  QKV  = (bf16*)(ws + 0);
  bf16*  Xbf  = (bf16*)(ws + 25165824);
  bf16*  AO   = (bf16*)(ws + 25165824);
  float* PROJ = (float*)(ws + 0);
  bf16*  H    = (bf16*)(ws + 0);
  bf16*  X1   = (bf16*)(ws + 33554432);
  bf16*  WT   = (bf16*)(ws + 41943040);
  float* BQKV = (float*)(ws + 48234496);

  const float QSCALE = 0.18033688f;  // (1/sqrt(64)) * log2(e)

  dim3 tb(32, 8);
  // phase 1: casts + QKV weights (wq pre-scaled for exp2-direct softmax)
  cast_f32_bf16<<<dim3(4096), dim3(256), 0, stream>>>(x, Xbf);
  transpose_k<<<dim3(32, 32), tb, 0, stream>>>(wq_w, WT, 1024, 1024, QSCALE);
  transpose_k<<<dim3(32, 32), tb, 0, stream>>>(wk_w, WT + 1024 * 1024, 1024, 1024, 1.0f);
  transpose_k<<<dim3(32, 32), tb, 0, stream>>>(wv_w, WT + 2 * 1024 * 1024, 1024, 1024, 1.0f);
  concat3<<<dim3(12), dim3(256), 0, stream>>>(wq_b, wk_b, wv_b, BQKV);
  // phase 2: fused QKV projection [4096,1024]@[3072,1024]^T -> bf16 (256² tile)
  gemm_bt256<<<dim3(12, 16), dim3(512), 0, stream>>>(Xbf, WT, BQKV, QKV, 1024, 3072, 0, 0);
  // phase 3: attention (512 blocks: 16 q-blocks x 32 bh, KVBLK=64)
  attn_kernel<<<dim3(16, 32), dim3(256), 0, stream>>>(QKV, mask, AO);
  // phase 4: output projection — BK=64 pipeline, split-K=2, fp32 atomic into PROJ
  transpose_k<<<dim3(32, 32), tb, 0, stream>>>(wo_w, WT, 1024, 1024, 1.0f);
  bias_init<<<dim3(4096), dim3(256), 0, stream>>>(wo_b, PROJ);
  gemm_pipe<<<dim3(8, 32, 2), dim3(256), 0, stream>>>(AO, WT, PROJ, 1024, 1024, 512);
  // phase 5: LN1 (a = PROJ fp32, xres = original fp32 x)
  ln_resid<<<dim3(4096), dim3(256), 0, stream>>>(PROJ, x, g1, be1, X1, 1, 1, 0);
  // phase 6: FFN up (256² tile, BK=64 double-buffered, 256 blocks = 1/CU)
  transpose_k<<<dim3(128, 32), tb, 0, stream>>>(f1w, WT, 1024, 4096, 1.0f);
  gemm_bt256<<<dim3(16, 16), dim3(512), 0, stream>>>(X1, WT, f1b, H, 1024, 4096, 1, 0);
  // phase 7: FFN down — BK=64 pipeline, split-K=2, fp32 atomic straight into d_out
  transpose_k<<<dim3(32, 128), tb, 0, stream>>>(f2w, WT, 4096, 1024, 1.0f);
  bias_init<<<dim3(4096), dim3(256), 0, stream>>>(f2b_, out);
  gemm_pipe<<<dim3(8, 32, 2), dim3(256), 0, stream>>>(H, WT, out, 4096, 1024, 2048);
  // phase 8: LN2 in-place on d_out (fp32 a, bf16 xres, fp32 out)
  ln_resid<<<dim3(4096), dim3(256), 0, stream>>>(out, X1, g2, be2, out, 1, 0, 1);
}

// Round 14
// 415.663 us; speedup vs baseline: 1.1423x; 1.0143x over previous
//
#include <hip/hip_runtime.h>
#include <hip/hip_bf16.h>
#include <cstdint>
#include <cstddef>

using bf16 = __hip_bfloat16;
typedef __attribute__((ext_vector_type(8))) short short8v;   // MFMA A/B frag: 8 bf16
typedef __attribute__((ext_vector_type(4))) short short4v;   // 4 bf16 (b64 load/store)
typedef __attribute__((ext_vector_type(4))) float float4v;   // MFMA C/D frag

__device__ inline float b2f(short s) {
  union { float f; uint32_t u; } z; z.u = ((uint32_t)(uint16_t)s) << 16; return z.f;
}
__device__ inline short f2b(float f) {
  bf16 h = __float2bfloat16(f);
  return *reinterpret_cast<short*>(&h);
}

typedef const __attribute__((address_space(1))) uint32_t* gas1p;
typedef __attribute__((address_space(3))) uint32_t* las3p;
__device__ inline void gload_lds16(const void* g, void* l) {
  __builtin_amdgcn_global_load_lds((gas1p)g, (las3p)l, 16, 0, 0);
}

// T1 XCD swizzle. Round-11 PMC confirmed: co-locates panel-sharing blocks on
// one XCD's L2 (gemm_pipe FETCH dropped 135 MB -> 32.8 MB compulsory).
__device__ inline void xcd_swizzle(int& bx, int& by, int& bz) {
  const int gx = gridDim.x, gy = gridDim.y;
  const int nwg = gx * gy * gridDim.z;
  const int wgid = blockIdx.x + gx * (blockIdx.y + gy * blockIdx.z);
  const int swz = (wgid & 7) * (nwg >> 3) + (wgid >> 3);
  bx = swz % gx;
  by = (swz / gx) % gy;
  bz = swz / (gx * gy);
}

// ---------------------------------------------------------------------------
// 128²-tile GEMM for QKV/FF1 (round 14): the round-12-proven gemm_pipe v4
// K-loop (BK=64 as two BK=32 halves, double-buffered LDS, ONE barrier/iter,
// XCD swizzle) + the proven gemm_bt bias/ReLU/bf16 epilogue. Replaces the
// 256²-tile gemm_bt256: round-13 PMC showed the 1-block/CU 256² schedule
// stall-bound at 443 TF, while FF2 (identical 34.4 GF) runs this loop
// UNDER 76 µs even with an fp32-atomic epilogue handicap — block-level
// parallelism (3-4/CU here) beats the 256² tile's traffic savings.
// C = A @ Bt^T + bias, optional ReLU. LDS 64 KB -> 2 blocks/CU resident.
// ---------------------------------------------------------------------------
__global__ __launch_bounds__(256) void gemm_bt128(
    const bf16* __restrict__ A, const bf16* __restrict__ Bt,
    const float* __restrict__ bias, void* __restrict__ C,
    int K, int ldc, int relu_mode, int out_f32) {
  __shared__ __align__(16) bf16 As[2][2][128 * 32];  // [buf][half][tile]
  __shared__ __align__(16) bf16 Bs[2][2][128 * 32];
  const int tid = threadIdx.x;
  const int w = tid >> 6, lane = tid & 63;
  const int quad = lane >> 4, l16 = lane & 15;
  const int wrow = (w >> 1) * 64, wcol = (w & 1) * 64;
  int bx, by, bz;
  xcd_swizzle(bx, by, bz);
  const int mbase = by * 128, nbase = bx * 128;
  const int c0 = w * 128 + lane;           // chunk ids c0 and c0+64
  const int row0 = c0 >> 2, p0 = c0 & 3;
  const int row1 = (c0 + 64) >> 2, p1 = (c0 + 64) & 3;

  const bf16* ag0 = A + (size_t)(mbase + row0) * K + p0 * 8;
  const bf16* ag1 = A + (size_t)(mbase + row1) * K + p1 * 8;
  const bf16* bg0 = Bt + (size_t)(nbase + row0) * K + p0 * 8;
  const bf16* bg1 = Bt + (size_t)(nbase + row1) * K + p1 * 8;

  // stage 64-col tile t64 into buffer bi (two BK=32 halves)
  auto stage = [&](int t64, int bi) {
    const int ko = t64 * 64;
#pragma unroll
    for (int h = 0; h < 2; h++) {
      char* da = (char*)As + (size_t)(bi * 2 + h) * 8192 + w * 2048;
      char* db = (char*)Bs + (size_t)(bi * 2 + h) * 8192 + w * 2048;
      gload_lds16(ag0 + ko + h * 32, da);
      gload_lds16(ag1 + ko + h * 32, da + 1024);
      gload_lds16(bg0 + ko + h * 32, db);
      gload_lds16(bg1 + ko + h * 32, db + 1024);
    }
  };

  float4v acc[4][4];
  for (int i = 0; i < 4; i++)
    for (int j = 0; j < 4; j++) acc[i][j] = (float4v){0.f, 0.f, 0.f, 0.f};

  const int KT2 = K >> 6;
  // prologue: tile 0 -> buf 0
  stage(0, 0);
  __syncthreads();

  for (int kt = 0; kt < KT2; kt++) {
    const int pb = kt & 1;
    if (kt + 1 < KT2) stage(kt + 1, 1 - pb);  // issued early, drained at barrier

#pragma unroll
    for (int h = 0; h < 2; h++) {
      const bf16* Ah = &As[pb][h][0];
      const bf16* Bh = &Bs[pb][h][0];
      short8v a[4], b[4];
      for (int mt = 0; mt < 4; mt++)
        a[mt] = *reinterpret_cast<const short8v*>(Ah + (wrow + mt * 16 + l16) * 32 + quad * 8);
      for (int nt = 0; nt < 4; nt++)
        b[nt] = *reinterpret_cast<const short8v*>(Bh + (wcol + nt * 16 + l16) * 32 + quad * 8);
      for (int mt = 0; mt < 4; mt++)
        for (int nt = 0; nt < 4; nt++)
          acc[mt][nt] = __builtin_amdgcn_mfma_f32_16x16x32_bf16(a[mt], b[nt], acc[mt][nt], 0, 0, 0);
    }

    __syncthreads();  // drains vmcnt (next tile valid) + lgkm (reads done)
  }

  // epilogue: D row = quad*4+reg, col = lane&15
  for (int nt = 0; nt < 4; nt++) {
    int col = nbase + wcol + nt * 16 + l16;
    float bv = bias[col];
    for (int mt = 0; mt < 4; mt++) {
      int row = mbase + wrow + mt * 16 + quad * 4;
      for (int r = 0; r < 4; r++) {
        float v = acc[mt][nt][r] + bv;
        if (relu_mode) v = fmaxf(v, 0.f);
        size_t idx = (size_t)(row + r) * ldc + col;
        if (out_f32) ((float*)C)[idx] = v;
        else         ((short*)C)[idx] = f2b(v);
      }
    }
  }
}

// ---------------------------------------------------------------------------
// Pipelined split-K GEMM for grid-limited shapes (WO, FF2). v4: BK=64 per
// barrier as two BK=32 halves, double-buffered, one barrier/iter, + T1 XCD
// swizzle. blockIdx.z selects a K-slice; partial sums atomicAdd into fp32 C.
// ---------------------------------------------------------------------------
__global__ __launch_bounds__(256) void gemm_pipe(
    const bf16* __restrict__ A, const bf16* __restrict__ Bt,
    float* __restrict__ C, int K, int ldc, int k_len) {
  __shared__ __align__(16) bf16 As[2][2][128 * 32];  // [buf][half][tile]
  __shared__ __align__(16) bf16 Bs[2][2][128 * 32];
  const int tid = threadIdx.x;
  const int w = tid >> 6, lane = tid & 63;
  const int quad = lane >> 4, l16 = lane & 15;
  const int wrow = (w >> 1) * 64, wcol = (w & 1) * 64;
  int bx, by, bz;
  xcd_swizzle(bx, by, bz);
  const int mbase = by * 128, nbase = bx * 128;
  const int c0 = w * 128 + lane;           // chunk ids c0 and c0+64
  const int row0 = c0 >> 2, p0 = c0 & 3;
  const int row1 = (c0 + 64) >> 2, p1 = (c0 + 64) & 3;
  const int kbase = bz * k_len;

  const bf16* ag0 = A + (size_t)(mbase + row0) * K + kbase + p0 * 8;
  const bf16* ag1 = A + (size_t)(mbase + row1) * K + kbase + p1 * 8;
  const bf16* bg0 = Bt + (size_t)(nbase + row0) * K + kbase + p0 * 8;
  const bf16* bg1 = Bt + (size_t)(nbase + row1) * K + kbase + p1 * 8;

  // stage 64-col tile t64 into buffer bi (two BK=32 halves)
  auto stage = [&](int t64, int bi) {
    const int ko = t64 * 64;
#pragma unroll
    for (int h = 0; h < 2; h++) {
      char* da = (char*)As + (size_t)(bi * 2 + h) * 8192 + w * 2048;
      char* db = (char*)Bs + (size_t)(bi * 2 + h) * 8192 + w * 2048;
      gload_lds16(ag0 + ko + h * 32, da);
      gload_lds16(ag1 + ko + h * 32, da + 1024);
      gload_lds16(bg0 + ko + h * 32, db);
      gload_lds16(bg1 + ko + h * 32, db + 1024);
    }
  };

  float4v acc[4][4];
  for (int i = 0; i < 4; i++)
    for (int j = 0; j < 4; j++) acc[i][j] = (float4v){0.f, 0.f, 0.f, 0.f};

  const int KT2 = k_len >> 6;
  // prologue: tile 0 -> buf 0
  stage(0, 0);
  __syncthreads();

  for (int kt = 0; kt < KT2; kt++) {
    const int pb = kt & 1;
    if (kt + 1 < KT2) stage(kt + 1, 1 - pb);  // issued early, drained at barrier

#pragma unroll
    for (int h = 0; h < 2; h++) {
      const bf16* Ah = &As[pb][h][0];
      const bf16* Bh = &Bs[pb][h][0];
      short8v a[4], b[4];
      for (int mt = 0; mt < 4; mt++)
        a[mt] = *reinterpret_cast<const short8v*>(Ah + (wrow + mt * 16 + l16) * 32 + quad * 8);
      for (int nt = 0; nt < 4; nt++)
        b[nt] = *reinterpret_cast<const short8v*>(Bh + (wcol + nt * 16 + l16) * 32 + quad * 8);
      for (int mt = 0; mt < 4; mt++)
        for (int nt = 0; nt < 4; nt++)
          acc[mt][nt] = __builtin_amdgcn_mfma_f32_16x16x32_bf16(a[mt], b[nt], acc[mt][nt], 0, 0, 0);
    }

    __syncthreads();  // drains vmcnt (next tile valid) + lgkm (reads done)
  }

  // epilogue: partial-sum atomicAdd (C pre-initialized with bias)
  for (int nt = 0; nt < 4; nt++) {
    int col = nbase + wcol + nt * 16 + l16;
    for (int mt = 0; mt < 4; mt++) {
      int row = mbase + wrow + mt * 16 + quad * 4;
      for (int r = 0; r < 4; r++)
        atomicAdd(&C[(size_t)(row + r) * ldc + col], acc[mt][nt][r]);
    }
  }
}

// C[row, 0..N) = bias[0..N), fp32. grid = rows, block 256, N = 1024.
__global__ __launch_bounds__(256) void bias_init(
    const float* __restrict__ bias, float* __restrict__ C) {
  int c = threadIdx.x * 4;
  float4 bv = *reinterpret_cast<const float4*>(bias + c);
  *reinterpret_cast<float4*>(C + (size_t)blockIdx.x * 1024 + c) = bv;
}

// ---------------------------------------------------------------------------
// Flash attention v10 (round 11, unchanged): 32 q/wave, 512 blocks, KVBLK=64
// (two 32-kv subtiles per barrier) — 32 iterations.
// ---------------------------------------------------------------------------
__global__ __launch_bounds__(256) void attn_kernel(
    const bf16* __restrict__ qkv, const int* __restrict__ mask,
    bf16* __restrict__ ao) {
  __shared__ __align__(16) short Vt[2][64 * 72];   // [buf][d][kv0..63], pitch 72
  __shared__ __align__(16) short Ks[2][64 * 64];   // [buf][kv][d], row-XOR-swizzled

  const int tid = threadIdx.x;
  const int w = tid >> 6, lane = tid & 63;
  const int quad = lane >> 4, l16 = lane & 15;
  const int bh = blockIdx.y, b = bh >> 4;
  const int row0 = bh * 128;                 // row base in qkv [4096,3072]
  const int qbase = blockIdx.x * 128 + w * 32;  // wave's 32 q rows
  const int kvp = tid & 15, dg = tid >> 4;   // V stager: kv rows 2kvp,2kvp+1; d 4dg..+3
  const int krow = tid >> 3, kc = tid & 7;   // K stager: rows krow & krow+32, chunk kc

  // Q fragments (B-operand of swapped QK^T); Q is pre-scaled by log2(e)/8
  short8v aq[2][2];
  for (int h = 0; h < 2; h++)
    for (int dh = 0; dh < 2; dh++) {
      int local = (qbase + h * 16 + l16) * 64 + dh * 32 + quad * 8;
      aq[h][dh] = *reinterpret_cast<const short8v*>(
          qkv + (size_t)(row0 + (local >> 10)) * 3072 + (local & 1023));
    }

  // K stage pointers (2 b128/thread cover the 64x64 tile)
  const bf16* pks0;
  {
    int local = krow * 64 + kc * 8;
    pks0 = qkv + (size_t)(row0 + (local >> 10)) * 3072 + (local & 1023) + 1024;
  }
  const bf16* pks1 = pks0 + 6144;
  // V stage pointers (2 kv rows x 4 d per thread, x2 subtiles)
  const bf16* pva;
  const bf16* pvb;
  {
    int la = (2 * kvp) * 64 + dg * 4;
    pva = qkv + (size_t)(row0 + (la >> 10)) * 3072 + (la & 1023) + 2048;
    int lb = (2 * kvp + 1) * 64 + dg * 4;
    pvb = qkv + (size_t)(row0 + (lb >> 10)) * 3072 + (lb & 1023) + 2048;
  }
  const bf16* pva2 = pva + 6144;
  const bf16* pvb2 = pvb + 6144;
  const int* pm = mask + b * 2048 + quad * 4;

  float4v o[2][4];
  for (int h = 0; h < 2; h++)
    for (int nt = 0; nt < 4; nt++) o[h][nt] = (float4v){0.f, 0.f, 0.f, 0.f};
  float4v lacc[2];
  lacc[0] = (float4v){0.f, 0.f, 0.f, 0.f};
  lacc[1] = (float4v){0.f, 0.f, 0.f, 0.f};
  short8v vone;
  for (int j = 0; j < 8; j++) vone[j] = (short)0x3F80;  // bf16 1.0 x8

  // prologue: load + stage tile 0 (64 kv rows)
  short8v kr0, kr1;
  short4v va, vb, va2, vb2;
  kr0 = *reinterpret_cast<const short8v*>(pks0);
  kr1 = *reinterpret_cast<const short8v*>(pks1);
  va  = *reinterpret_cast<const short4v*>(pva);
  vb  = *reinterpret_cast<const short4v*>(pvb);
  va2 = *reinterpret_cast<const short4v*>(pva2);
  vb2 = *reinterpret_cast<const short4v*>(pvb2);
  int4 mc0 = *reinterpret_cast<const int4*>(pm);
  int4 mc1 = *reinterpret_cast<const int4*>(pm + 16);
  int4 mc2 = *reinterpret_cast<const int4*>(pm + 32);
  int4 mc3 = *reinterpret_cast<const int4*>(pm + 48);
  pks0 += 12288; pks1 += 12288; pva += 12288; pvb += 12288;
  pva2 += 12288; pvb2 += 12288; pm += 64;
  {
    const int sw = (kc ^ (krow & 7)) << 3;
    *reinterpret_cast<short8v*>(&Ks[0][krow * 64 + sw]) = kr0;
    *reinterpret_cast<short8v*>(&Ks[0][(krow + 32) * 64 + sw]) = kr1;
    uint32_t* vt = reinterpret_cast<uint32_t*>(&Vt[0][0]);
    for (int i = 0; i < 4; i++) {
      vt[(dg * 4 + i) * 36 + kvp] =
          ((uint32_t)(uint16_t)vb[i] << 16) | (uint16_t)(uint16_t)va[i];
      vt[(dg * 4 + i) * 36 + 16 + kvp] =
          ((uint32_t)(uint16_t)vb2[i] << 16) | (uint16_t)(uint16_t)va2[i];
    }
  }
  __syncthreads();

  for (int it = 0; it < 32; it++) {
    const int pb = it & 1;
    short8v knr0, knr1;
    short4v vna, vnb, vna2, vnb2;
    int4 mn0, mn1, mn2, mn3;
    if (it < 31) {
      knr0 = *reinterpret_cast<const short8v*>(pks0);
      knr1 = *reinterpret_cast<const short8v*>(pks1);
      vna  = *reinterpret_cast<const short4v*>(pva);
      vnb  = *reinterpret_cast<const short4v*>(pvb);
      vna2 = *reinterpret_cast<const short4v*>(pva2);
      vnb2 = *reinterpret_cast<const short4v*>(pvb2);
      mn0 = *reinterpret_cast<const int4*>(pm);
      mn1 = *reinterpret_cast<const int4*>(pm + 16);
      mn2 = *reinterpret_cast<const int4*>(pm + 32);
      mn3 = *reinterpret_cast<const int4*>(pm + 48);
      pks0 += 12288; pks1 += 12288; pva += 12288; pvb += 12288;
      pva2 += 12288; pvb2 += 12288; pm += 64;
    }

#pragma unroll
    for (int sub = 0; sub < 2; sub++) {
      // K fragments from LDS (swizzled read: chunk (dh*4+quad) ^ (l16&7))
      short8v kc_[2][2];
      for (int s = 0; s < 2; s++)
        for (int dh = 0; dh < 2; dh++) {
          int rr = sub * 32 + s * 16 + l16;
          kc_[s][dh] = *reinterpret_cast<const short8v*>(
              &Ks[pb][rr * 64 + (((dh * 4 + quad) ^ (l16 & 7)) << 3)]);
        }

      float4v st[2][2];
      for (int s = 0; s < 2; s++)
        for (int h = 0; h < 2; h++) {
          float4v t = (float4v){0.f, 0.f, 0.f, 0.f};
          t = __builtin_amdgcn_mfma_f32_16x16x32_bf16(kc_[s][0], aq[h][0], t, 0, 0, 0);
          t = __builtin_amdgcn_mfma_f32_16x16x32_bf16(kc_[s][1], aq[h][1], t, 0, 0, 0);
          st[s][h] = t;
        }

      // softmax numerator + in-register P-fragment assembly (no LDS)
      short8v pf[2];
      for (int h = 0; h < 2; h++) {
        float ev[2][4];
        for (int s = 0; s < 2; s++) {
          int4 mv = sub ? (s ? mc3 : mc2) : (s ? mc1 : mc0);
          int mm[4] = {mv.x, mv.y, mv.z, mv.w};
          for (int r = 0; r < 4; r++) {
            float y = st[s][h][r];                    // already exp2-arg units
            y = (mm[r] == 0) ? -1.4427e-12f : y;      // faithful mask semantics
            ev[s][r] = __builtin_amdgcn_exp2f(y);
          }
        }
        uint32_t a0, a1, b0, b1;
        asm("v_cvt_pk_bf16_f32 %0, %1, %2" : "=v"(a0) : "v"(ev[0][0]), "v"(ev[0][1]));
        asm("v_cvt_pk_bf16_f32 %0, %1, %2" : "=v"(a1) : "v"(ev[0][2]), "v"(ev[0][3]));
        asm("v_cvt_pk_bf16_f32 %0, %1, %2" : "=v"(b0) : "v"(ev[1][0]), "v"(ev[1][1]));
        asm("v_cvt_pk_bf16_f32 %0, %1, %2" : "=v"(b1) : "v"(ev[1][2]), "v"(ev[1][3]));
        // halves: lanes<32 hold A-family (s=0), >=32 B-family (s=1)
        asm("v_permlane32_swap_b32 %0, %1" : "+v"(b0), "+v"(a0));
        asm("v_permlane16_swap_b32 %0, %1" : "+v"(b0), "+v"(a0));
        asm("v_permlane32_swap_b32 %0, %1" : "+v"(b1), "+v"(a1));
        asm("v_permlane16_swap_b32 %0, %1" : "+v"(b1), "+v"(a1));
        union { short8v s8; uint32_t u[4]; } pfu;
        pfu.u[0] = a0; pfu.u[1] = a1; pfu.u[2] = b0; pfu.u[3] = b1;
        pf[h] = pfu.s8;
      }

      for (int h = 0; h < 2; h++)
        lacc[h] = __builtin_amdgcn_mfma_f32_16x16x32_bf16(pf[h], vone, lacc[h], 0, 0, 0);
      for (int nt = 0; nt < 4; nt++) {
        short8v bv = *reinterpret_cast<const short8v*>(
            &Vt[pb][(nt * 16 + l16) * 72 + sub * 32 + quad * 8]);
        for (int h = 0; h < 2; h++)
          o[h][nt] = __builtin_amdgcn_mfma_f32_16x16x32_bf16(pf[h], bv, o[h][nt], 0, 0, 0);
      }
    }

    if (it < 31) {
      const int sw = (kc ^ (krow & 7)) << 3;
      *reinterpret_cast<short8v*>(&Ks[1 - pb][krow * 64 + sw]) = knr0;
      *reinterpret_cast<short8v*>(&Ks[1 - pb][(krow + 32) * 64 + sw]) = knr1;
      uint32_t* vt = reinterpret_cast<uint32_t*>(&Vt[1 - pb][0]);
      for (int i = 0; i < 4; i++) {
        vt[(dg * 4 + i) * 36 + kvp] =
            ((uint32_t)(uint16_t)vnb[i] << 16) | (uint16_t)(uint16_t)vna[i];
        vt[(dg * 4 + i) * 36 + 16 + kvp] =
            ((uint32_t)(uint16_t)vnb2[i] << 16) | (uint16_t)(uint16_t)vna2[i];
      }
      mc0 = mn0; mc1 = mn1; mc2 = mn2; mc3 = mn3;
    }
    __syncthreads();
  }

  // lacc[h][r] = rowsum(P) for q row quad*4+r (all 16 cols identical)
  for (int h = 0; h < 2; h++)
    for (int r = 0; r < 4; r++) {
      float linv = 1.0f / lacc[h][r];
      int qg = qbase + h * 16 + quad * 4 + r;
      for (int nt = 0; nt < 4; nt++) {
        int d = nt * 16 + l16;
        ao[(size_t)bh * 131072 + (size_t)qg * 64 + d] = __float2bfloat16(o[h][nt][r] * linv);
      }
    }
}

// ---------------------------------------------------------------------------
// out = LN(a + xres); unbiased std (ddof=1), /(std + 1e-12). One block / row.
// ---------------------------------------------------------------------------
__global__ __launch_bounds__(256) void ln_resid(
    const void* __restrict__ a, const void* __restrict__ xres,
    const float* __restrict__ gamma, const float* __restrict__ beta,
    void* __restrict__ out, int a_f32, int x_f32, int out_f32) {
  __shared__ float red[8];
  const int row = blockIdx.x, tid = threadIdx.x;
  const int w = tid >> 6, lane = tid & 63;
  const size_t base = (size_t)row * 1024;
  float v[4]; float sum = 0.f, ss = 0.f;
  for (int i = 0; i < 4; i++) {
    int c = tid + i * 256;
    float av = a_f32 ? ((const float*)a)[base + c] : b2f(((const short*)a)[base + c]);
    float xv = x_f32 ? ((const float*)xres)[base + c] : b2f(((const short*)xres)[base + c]);
    v[i] = av + xv;
    sum += v[i]; ss += v[i] * v[i];
  }
  for (int off = 1; off < 64; off <<= 1) {
    sum += __shfl_xor(sum, off);
    ss  += __shfl_xor(ss, off);
  }
  if (lane == 0) { red[w * 2] = sum; red[w * 2 + 1] = ss; }
  __syncthreads();
  sum = red[0] + red[2] + red[4] + red[6];
  ss  = red[1] + red[3] + red[5] + red[7];
  float mean = sum * (1.0f / 1024.0f);
  float var = (ss - 1024.0f * mean * mean) * (1.0f / 1023.0f);
  var = fmaxf(var, 0.f);
  float rden = 1.0f / (sqrtf(var) + 1e-12f);
  for (int i = 0; i < 4; i++) {
    int c = tid + i * 256;
    float y = gamma[c] * ((v[i] - mean) * rden) + beta[c];
    if (out_f32) ((float*)out)[base + c] = y;
    else         ((short*)out)[base + c] = f2b(y);
  }
}

// out(bf16)[c*R + r] = in(f32)[r*C + c] * scale; R,C % 32 == 0.
__global__ __launch_bounds__(256) void transpose_k(
    const float* __restrict__ in, bf16* __restrict__ out, int R, int C,
    float scale) {
  __shared__ short t[32][33];
  const int tx = threadIdx.x, ty = threadIdx.y;
  const int cb = blockIdx.x * 32, rb = blockIdx.y * 32;
  for (int j = 0; j < 4; j++)
    t[ty + j * 8][tx] = f2b(in[(size_t)(rb + ty + j * 8) * C + cb + tx] * scale);
  __syncthreads();
  for (int j = 0; j < 4; j++)
    ((short*)out)[(size_t)(cb + ty + j * 8) * R + rb + tx] = t[tx][ty + j * 8];
}

// q-bias scaled by log2(e)/8 to match the pre-scaled Q projection.
__global__ __launch_bounds__(256) void concat3(
    const float* __restrict__ a, const float* __restrict__ b,
    const float* __restrict__ c, float* __restrict__ out) {
  int i = blockIdx.x * 256 + threadIdx.x;  // grid 12 -> 3072
  float v;
  if (i < 1024)       v = a[i] * 0.18033688f;
  else if (i < 2048)  v = b[i - 1024];
  else                v = c[i - 2048];
  out[i] = v;
}

__global__ __launch_bounds__(256) void cast_f32_bf16(
    const float* __restrict__ in, bf16* __restrict__ out) {
  int i0 = (blockIdx.x * 256 + threadIdx.x) * 4;
  float4 f = *reinterpret_cast<const float4*>(in + i0);
  short* o = (short*)out + i0;
  o[0] = f2b(f.x); o[1] = f2b(f.y); o[2] = f2b(f.z); o[3] = f2b(f.w);
}

// ---------------------------------------------------------------------------
extern "C" void kernel_launch(void* const* d_in, const int* in_sizes, int n_in,
                              void* d_out, int out_size, void* d_ws, size_t ws_size,
                              hipStream_t stream) {
  (void)in_sizes; (void)n_in; (void)out_size; (void)ws_size;
  const float* x    = (const float*)d_in[0];
  const int*   mask = (const int*)d_in[1];
  const float* wq_w = (const float*)d_in[2];
  const float* wq_b = (const float*)d_in[3];
  const float* wk_w = (const float*)d_in[4];
  const float* wk_b = (const float*)d_in[5];
  const float* wv_w = (const float*)d_in[6];
  const float* wv_b = (const float*)d_in[7];
  const float* wo_w = (const float*)d_in[8];
  const float* wo_b = (const float*)d_in[9];
  const float* g1   = (const float*)d_in[10];
  const float* be1  = (const float*)d_in[11];
  const float* f1w  = (const float*)d_in[12];
  const float* f1b  = (const float*)d_in[13];
  const float* f2w  = (const float*)d_in[14];
  const float* f2b_ = (const float*)d_in[15];
  const float* g2   = (const float*)d_in[16];
  const float* be2  = (const float*)d_in[17];
  float* out = (float*)d_out;
  char* ws = (char*)d_ws;

  // ws layout (peak 48 MiB, time-shared):
  //  [0,24M)   QKV (ph2-3) -> PROJ fp32 [0,16M) (ph4-5) -> H [0,32M) (ph6-7)
  //  [24M,32M) Xbf (ph1-2) -> AO (ph3-4)
  //  [32M,40M) X1  (ph5-8)
  //  [40M,48M) WT  (transposed weights, per-phase)  + BQKV fp32 tail
  bf16*  QKV  = (bf16*)(ws + 0);
  bf16*  Xbf  = (bf16*)(ws + 25165824);
  bf16*  AO   = (bf16*)(ws + 25165824);
  float* PROJ = (float*)(ws + 0);
  bf16*  H    = (bf16*)(ws + 0);
  bf16*  X1   = (bf16*)(ws + 33554432);
  bf16*  WT   = (bf16*)(ws + 41943040);
  float* BQKV = (float*)(ws + 48234496);

  const float QSCALE = 0.18033688f;  // (1/sqrt(64)) * log2(e)

  dim3 tb(32, 8);
  // phase 1: casts + QKV weights (wq pre-scaled for exp2-direct softmax)
  cast_f32_bf16<<<dim3(4096), dim3(256), 0, stream>>>(x, Xbf);
  transpose_k<<<dim3(32, 32), tb, 0, stream>>>(wq_w, WT, 1024, 1024, QSCALE);
  transpose_k<<<dim3(32, 32), tb, 0, stream>>>(wk_w, WT + 1024 * 1024, 1024, 1024, 1.0f);
  transpose_k<<<dim3(32, 32), tb, 0, stream>>>(wv_w, WT + 2 * 1024 * 1024, 1024, 1024, 1.0f);
  concat3<<<dim3(12), dim3(256), 0, stream>>>(wq_b, wk_b, wv_b, BQKV);
  // phase 2: fused QKV projection — 128² BK=64 pipeline, 768 blocks (3/CU)
  gemm_bt128<<<dim3(24, 32), dim3(256), 0, stream>>>(Xbf, WT, BQKV, QKV, 1024, 3072, 0, 0);
  // phase 3: attention (512 blocks: 16 q-blocks x 32 bh, KVBLK=64)
  attn_kernel<<<dim3(16, 32), dim3(256), 0, stream>>>(QKV, mask, AO);
  // phase 4: output projection — BK=64 pipeline, split-K=2, fp32 atomic into PROJ
  transpose_k<<<dim3(32, 32), tb, 0, stream>>>(wo_w, WT, 1024, 1024, 1.0f);
  bias_init<<<dim3(4096), dim3(256), 0, stream>>>(wo_b, PROJ);
  gemm_pipe<<<dim3(8, 32, 2), dim3(256), 0, stream>>>(AO, WT, PROJ, 1024, 1024, 512);
  // phase 5: LN1 (a = PROJ fp32, xres = original fp32 x)
  ln_resid<<<dim3(4096), dim3(256), 0, stream>>>(PROJ, x, g1, be1, X1, 1, 1, 0);
  // phase 6: FFN up — 128² BK=64 pipeline, 1024 blocks (4/CU)
  transpose_k<<<dim3(128, 32), tb, 0, stream>>>(f1w, WT, 1024, 4096, 1.0f);
  gemm_bt128<<<dim3(32, 32), dim3(256), 0, stream>>>(X1, WT, f1b, H, 1024, 4096, 1, 0);
  // phase 7: FFN down — BK=64 pipeline, split-K=2, fp32 atomic straight into d_out
  transpose_k<<<dim3(32, 128), tb, 0, stream>>>(f2w, WT, 4096, 1024, 1.0f);
  bias_init<<<dim3(4096), dim3(256), 0, stream>>>(f2b_, out);
  gemm_pipe<<<dim3(8, 32, 2), dim3(256), 0, stream>>>(H, WT, out, 4096, 1024, 2048);
  // phase 8: LN2 in-place on d_out (fp32 a, bf16 xres, fp32 out)
  ln_resid<<<dim3(4096), dim3(256), 0, stream>>>(out, X1, g2, be2, out, 1, 0, 1);
}